// Round 1
// baseline (880.977 us; speedup 1.0000x reference)
//
#include <hip/hip_runtime.h>
#include <stdint.h>

#define B_  2
#define T_  2048
#define C_  2048
#define NH  16
#define HD  128
#define M_  (B_*T_)   // 4096

typedef unsigned short ushort_t;
typedef __attribute__((ext_vector_type(8))) short short8;
typedef __attribute__((ext_vector_type(4))) float f32x4;

__device__ inline ushort_t f2b(float f) {
  union { float f; unsigned u; } x; x.f = f;
  unsigned r = (x.u + 0x7fffu + ((x.u >> 16) & 1u)) >> 16;
  return (ushort_t)r;
}
__device__ inline float b2f(ushort_t b) {
  union { unsigned u; float f; } x; x.u = ((unsigned)b) << 16;
  return x.f;
}
__device__ inline void gload_lds16(const void* g, void* l) {
  __builtin_amdgcn_global_load_lds((const __attribute__((address_space(1))) void*)g,
                                   (__attribute__((address_space(3))) void*)l, 16, 0, 0);
}

// ---------------- x fp32 -> bf16 ----------------
__global__ __launch_bounds__(256) void cvt_f32_bf16(const float* __restrict__ in,
                                                    ushort_t* __restrict__ out, int n4) {
  int i = blockIdx.x * 256 + threadIdx.x;
  if (i >= n4) return;
  float4 v = ((const float4*)in)[i];
  unsigned long long pk = (unsigned long long)f2b(v.x)
                        | ((unsigned long long)f2b(v.y) << 16)
                        | ((unsigned long long)f2b(v.z) << 32)
                        | ((unsigned long long)f2b(v.w) << 48);
  ((unsigned long long*)out)[i] = pk;
}

// ---------------- transpose (+convert) to bf16, out[(col)*rows + row] ----------------
template<int FROM_F32>
__global__ __launch_bounds__(256) void transpose_to_bf16(const void* __restrict__ inv,
                                                         ushort_t* __restrict__ out,
                                                         int rows, int cols) {
  __shared__ __align__(16) ushort_t tile[64][65];
  const int t = threadIdx.x;
  const int br = blockIdx.y * 64, bc = blockIdx.x * 64;
#pragma unroll
  for (int i = 0; i < 16; i++) {
    int idx = i * 256 + t, r = idx >> 6, c = idx & 63;
    ushort_t v;
    if (FROM_F32) v = f2b(((const float*)inv)[(size_t)(br + r) * cols + bc + c]);
    else          v = ((const ushort_t*)inv)[(size_t)(br + r) * cols + bc + c];
    tile[r][c] = v;
  }
  __syncthreads();
#pragma unroll
  for (int i = 0; i < 16; i++) {
    int idx = i * 256 + t, r = idx >> 6, c = idx & 63;
    out[(size_t)(bc + r) * rows + br + c] = tile[c][r];
  }
}

// ---------------- RoPE cos/sin table: [T_][64] ----------------
__global__ __launch_bounds__(256) void rope_table(float* __restrict__ cs, float* __restrict__ sn) {
  int i = blockIdx.x * 256 + threadIdx.x;   // T_*64
  int tt = i >> 6, f = i & 63;
  float inv = powf(10000.0f, -(float)(2 * f) / 128.0f);
  float ang = (float)tt * inv;
  cs[i] = cosf(ang);
  sn[i] = sinf(ang);
}

// ---------------- RoPE apply in place on Q and K (bf16) ----------------
__global__ __launch_bounds__(256) void rope_apply(ushort_t* __restrict__ Q, ushort_t* __restrict__ K,
                                                  const float* __restrict__ cs,
                                                  const float* __restrict__ sn) {
  int i = blockIdx.x * 256 + threadIdx.x;   // M_ * 1024 pairs
  int row = i >> 10, p = i & 1023, f = p & 63, tt = row & (T_ - 1);
  float c = cs[(tt << 6) + f], s = sn[(tt << 6) + f];
  size_t idx = ((size_t)row << 11) + 2 * p;
  float qr = b2f(Q[idx]), qi = b2f(Q[idx + 1]);
  Q[idx]     = f2b(qr * c - qi * s);
  Q[idx + 1] = f2b(qr * s + qi * c);
  float kr = b2f(K[idx]), ki = b2f(K[idx + 1]);
  K[idx]     = f2b(kr * c - ki * s);
  K[idx + 1] = f2b(kr * s + ki * c);
}

// ---------------- GEMM: C[M,N] = A[M,K] (bf16, row-major) @ Bt[N,K]^T (bf16) ----------------
// m97 structure: 128x128 tile, BK=64, 4 waves (2x2), global_load_lds width 16.
template<int OUTF32>
__global__ __launch_bounds__(256) void gemm_bt(const ushort_t* __restrict__ A,
                                               const ushort_t* __restrict__ Bt0,
                                               const ushort_t* __restrict__ Bt1,
                                               const ushort_t* __restrict__ Bt2,
                                               void* __restrict__ O0, void* __restrict__ O1,
                                               void* __restrict__ O2, int N, int K) {
  const int z = blockIdx.z;
  const ushort_t* Bt = (z == 0) ? Bt0 : (z == 1) ? Bt1 : Bt2;
  void* Ov = (z == 0) ? O0 : (z == 1) ? O1 : O2;
  const int t = threadIdx.x;
  const int lane = t & 63, wave = t >> 6;
  const int wr = wave >> 1, wc = wave & 1;
  const int lr = lane & 15, lg = lane >> 4;
  const int bm = blockIdx.y, bn = blockIdx.x;
  __shared__ __align__(16) ushort_t As[128 * 64];
  __shared__ __align__(16) ushort_t Bs[128 * 64];
  f32x4 acc[4][4] = {};
  const ushort_t* Ap = A + (size_t)bm * 128 * K;
  const ushort_t* Bp = Bt + (size_t)bn * 128 * K;
  for (int k0 = 0; k0 < K; k0 += 64) {
#pragma unroll
    for (int i = 0; i < 4; i++) {
      int chunk = i * 256 + t;
      int row = chunk >> 3, kc = chunk & 7;
      gload_lds16(Ap + (size_t)row * K + k0 + kc * 8, &As[(size_t)(i * 256 + wave * 64) * 8]);
      gload_lds16(Bp + (size_t)row * K + k0 + kc * 8, &Bs[(size_t)(i * 256 + wave * 64) * 8]);
    }
    __syncthreads();
#pragma unroll
    for (int kk = 0; kk < 64; kk += 32) {
      short8 af[4], bf[4];
#pragma unroll
      for (int i = 0; i < 4; i++) {
        af[i] = *(const short8*)&As[(wr * 64 + i * 16 + lr) * 64 + kk + lg * 8];
        bf[i] = *(const short8*)&Bs[(wc * 64 + i * 16 + lr) * 64 + kk + lg * 8];
      }
#pragma unroll
      for (int i = 0; i < 4; i++)
#pragma unroll
        for (int j = 0; j < 4; j++)
          acc[i][j] = __builtin_amdgcn_mfma_f32_16x16x32_bf16(af[i], bf[j], acc[i][j], 0, 0, 0);
    }
    __syncthreads();
  }
  const int row0 = bm * 128 + wr * 64 + lg * 4;
  const int col0 = bn * 128 + wc * 64 + lr;
  if (OUTF32) {
    float* O = (float*)Ov;
#pragma unroll
    for (int i = 0; i < 4; i++)
#pragma unroll
      for (int j = 0; j < 4; j++)
#pragma unroll
        for (int r = 0; r < 4; r++)
          O[(size_t)(row0 + i * 16 + r) * N + col0 + j * 16] = acc[i][j][r];
  } else {
    ushort_t* O = (ushort_t*)Ov;
#pragma unroll
    for (int i = 0; i < 4; i++)
#pragma unroll
      for (int j = 0; j < 4; j++)
#pragma unroll
        for (int r = 0; r < 4; r++)
          O[(size_t)(row0 + i * 16 + r) * N + col0 + j * 16] = f2b(acc[i][j][r]);
  }
}

// ---------------- Flash attention ----------------
// grid: (T_/64, B_*NH); block 256 = 4 waves; wave handles 16 q rows.
// Q,K: (B*T, C) bf16 (head h at col h*128). Vt: per (b,h): [128 d][T] bf16.
__global__ __launch_bounds__(256) void flash_attn(const ushort_t* __restrict__ Q,
                                                  const ushort_t* __restrict__ K,
                                                  const ushort_t* __restrict__ Vt,
                                                  ushort_t* __restrict__ AO) {
  const int bh = blockIdx.y, b = bh >> 4, h = bh & 15;
  const int wave = threadIdx.x >> 6, lane = threadIdx.x & 63;
  const int lr = lane & 15, lg = lane >> 4;
  const int q0 = blockIdx.x * 64 + wave * 16;
  const ushort_t* Qb = Q + (size_t)b * T_ * C_ + (size_t)h * HD;
  const ushort_t* Kb = K + (size_t)b * T_ * C_ + (size_t)h * HD;
  const ushort_t* Vb = Vt + (size_t)bh * HD * T_;
  __shared__ __align__(16) ushort_t plds[4][16 * 32];
  ushort_t* myp = plds[wave];

  short8 qf[4];
#pragma unroll
  for (int di = 0; di < 4; di++)
    qf[di] = *(const short8*)&Qb[(size_t)(q0 + lr) * C_ + di * 32 + lg * 8];

  f32x4 o[8] = {};
  float m[4], l[4];
#pragma unroll
  for (int r = 0; r < 4; r++) { m[r] = -1e30f; l[r] = 0.f; }
  const float sc = 0.12754245f;  // log2(e)/sqrt(128)
  const int kend = q0 + 16;

  for (int k0 = 0; k0 < kend; k0 += 32) {
    f32x4 s0 = {}, s1 = {};
#pragma unroll
    for (int di = 0; di < 4; di++) {
      short8 kf0 = *(const short8*)&Kb[(size_t)(k0 + lr) * C_ + di * 32 + lg * 8];
      short8 kf1 = *(const short8*)&Kb[(size_t)(k0 + 16 + lr) * C_ + di * 32 + lg * 8];
      s0 = __builtin_amdgcn_mfma_f32_16x16x32_bf16(qf[di], kf0, s0, 0, 0, 0);
      s1 = __builtin_amdgcn_mfma_f32_16x16x32_bf16(qf[di], kf1, s1, 0, 0, 0);
    }
    const int qrow = q0 + lg * 4;
    float tm[4], rs[4];
#pragma unroll
    for (int r = 0; r < 4; r++) {
      float v0 = s0[r] * sc, v1 = s1[r] * sc;
      if (k0 + lr      > qrow + r) v0 = -1e30f;
      if (k0 + 16 + lr > qrow + r) v1 = -1e30f;
      s0[r] = v0; s1[r] = v1;
      tm[r] = fmaxf(v0, v1);
    }
#pragma unroll
    for (int off = 1; off < 16; off <<= 1)
#pragma unroll
      for (int r = 0; r < 4; r++)
        tm[r] = fmaxf(tm[r], __shfl_xor(tm[r], off, 64));
    float corr[4];
#pragma unroll
    for (int r = 0; r < 4; r++) {
      float mn = fmaxf(m[r], tm[r]);
      corr[r] = exp2f(m[r] - mn);
      m[r] = mn;
    }
#pragma unroll
    for (int r = 0; r < 4; r++) {
      float p0 = exp2f(s0[r] - m[r]);
      float p1 = exp2f(s1[r] - m[r]);
      s0[r] = p0; s1[r] = p1;
      rs[r] = p0 + p1;
    }
#pragma unroll
    for (int off = 1; off < 16; off <<= 1)
#pragma unroll
      for (int r = 0; r < 4; r++)
        rs[r] += __shfl_xor(rs[r], off, 64);
#pragma unroll
    for (int r = 0; r < 4; r++) l[r] = l[r] * corr[r] + rs[r];
#pragma unroll
    for (int dc = 0; dc < 8; dc++)
#pragma unroll
      for (int r = 0; r < 4; r++) o[dc][r] *= corr[r];
    // P (C-layout) -> LDS -> A-layout fragment
#pragma unroll
    for (int r = 0; r < 4; r++) {
      myp[(lg * 4 + r) * 32 + lr]      = f2b(s0[r]);
      myp[(lg * 4 + r) * 32 + 16 + lr] = f2b(s1[r]);
    }
    short8 pa = *(const short8*)&myp[lr * 32 + lg * 8];
#pragma unroll
    for (int dc = 0; dc < 8; dc++) {
      short8 vb = *(const short8*)&Vb[(size_t)(dc * 16 + lr) * T_ + k0 + lg * 8];
      o[dc] = __builtin_amdgcn_mfma_f32_16x16x32_bf16(pa, vb, o[dc], 0, 0, 0);
    }
  }
#pragma unroll
  for (int dc = 0; dc < 8; dc++)
#pragma unroll
    for (int r = 0; r < 4; r++) {
      float val = o[dc][r] / l[r];
      AO[(size_t)(b * T_ + q0 + lg * 4 + r) * C_ + h * HD + dc * 16 + lr] = f2b(val);
    }
}

extern "C" void kernel_launch(void* const* d_in, const int* in_sizes, int n_in,
                              void* d_out, int out_size, void* d_ws, size_t ws_size,
                              hipStream_t stream) {
  const float* x  = (const float*)d_in[0];
  // d_in[1] = mask (causal tril) — implicit in the kernel
  const float* wq = (const float*)d_in[2];
  const float* wk = (const float*)d_in[3];
  const float* wv = (const float*)d_in[4];
  const float* wo = (const float*)d_in[5];

  char* ws = (char*)d_ws;
  size_t off = 0;
  auto alloc = [&](size_t bytes) { char* p = ws + off; off += (bytes + 255) & ~255ull; return p; };
  ushort_t* Qb  = (ushort_t*)alloc((size_t)M_ * C_ * 2);
  ushort_t* Kb  = (ushort_t*)alloc((size_t)M_ * C_ * 2);
  ushort_t* Vb  = (ushort_t*)alloc((size_t)M_ * C_ * 2);
  ushort_t* Vtb = (ushort_t*)alloc((size_t)M_ * C_ * 2);
  ushort_t* xb  = (ushort_t*)alloc((size_t)M_ * C_ * 2);
  ushort_t* AO  = xb;  // alias: xb dead after QKV GEMM; AO written by flash_attn afterwards
  ushort_t* wqt = (ushort_t*)alloc((size_t)C_ * C_ * 2);
  ushort_t* wkt = (ushort_t*)alloc((size_t)C_ * C_ * 2);
  ushort_t* wvt = (ushort_t*)alloc((size_t)C_ * C_ * 2);
  ushort_t* wot = (ushort_t*)alloc((size_t)C_ * C_ * 2);
  float* cs = (float*)alloc((size_t)T_ * 64 * 4);
  float* sn = (float*)alloc((size_t)T_ * 64 * 4);

  // 1. x -> bf16
  cvt_f32_bf16<<<(M_ * C_ / 4 + 255) / 256, 256, 0, stream>>>(x, xb, M_ * C_ / 4);
  // 2. weights -> bf16 transposed (N,K)
  dim3 tg(C_ / 64, C_ / 64);
  transpose_to_bf16<1><<<tg, 256, 0, stream>>>(wq, wqt, C_, C_);
  transpose_to_bf16<1><<<tg, 256, 0, stream>>>(wk, wkt, C_, C_);
  transpose_to_bf16<1><<<tg, 256, 0, stream>>>(wv, wvt, C_, C_);
  transpose_to_bf16<1><<<tg, 256, 0, stream>>>(wo, wot, C_, C_);
  // 3. RoPE tables
  rope_table<<<T_ * 64 / 256, 256, 0, stream>>>(cs, sn);
  // 4. QKV projections
  gemm_bt<0><<<dim3(C_ / 128, M_ / 128, 3), 256, 0, stream>>>(xb, wqt, wkt, wvt,
                                                              Qb, Kb, Vb, C_, C_);
  // 5. RoPE on Q, K
  rope_apply<<<M_ * 1024 / 256, 256, 0, stream>>>(Qb, Kb, cs, sn);
  // 6. V -> Vt per batch (2048x2048 transpose each)
  for (int b = 0; b < B_; b++)
    transpose_to_bf16<0><<<dim3(T_ / 64, T_ / 64), 256, 0, stream>>>(
        Vb + (size_t)b * T_ * C_, Vtb + (size_t)b * T_ * C_, T_, C_);
  // 7. flash attention
  flash_attn<<<dim3(T_ / 64, B_ * NH), 256, 0, stream>>>(Qb, Kb, Vtb, AO);
  // 8. output projection -> fp32 d_out
  gemm_bt<1><<<dim3(C_ / 128, M_ / 128, 1), 256, 0, stream>>>(AO, wot, wot, wot,
                                                              d_out, d_out, d_out, C_, C_);
  (void)in_sizes; (void)n_in; (void)out_size; (void)ws_size;
}

// Round 2
// 634.804 us; speedup vs baseline: 1.3878x; 1.3878x over previous
//
#include <hip/hip_runtime.h>
#include <stdint.h>

#define B_  2
#define T_  2048
#define C_  2048
#define NH  16
#define HD  128
#define M_  (B_*T_)   // 4096

typedef unsigned short ushort_t;
typedef __attribute__((ext_vector_type(8))) short short8;
typedef __attribute__((ext_vector_type(4))) float f32x4;

__device__ inline ushort_t f2b(float f) {
  union { float f; unsigned u; } x; x.f = f;
  unsigned r = (x.u + 0x7fffu + ((x.u >> 16) & 1u)) >> 16;
  return (ushort_t)r;
}
__device__ inline float b2f(ushort_t b) {
  union { unsigned u; float f; } x; x.u = ((unsigned)b) << 16;
  return x.f;
}
__device__ inline void gload_lds16(const void* g, void* l) {
  __builtin_amdgcn_global_load_lds((const __attribute__((address_space(1))) void*)g,
                                   (__attribute__((address_space(3))) void*)l, 16, 0, 0);
}

// ---------------- x fp32 -> bf16 ----------------
__global__ __launch_bounds__(256) void cvt_f32_bf16(const float* __restrict__ in,
                                                    ushort_t* __restrict__ out, int n4) {
  int i = blockIdx.x * 256 + threadIdx.x;
  if (i >= n4) return;
  float4 v = ((const float4*)in)[i];
  unsigned long long pk = (unsigned long long)f2b(v.x)
                        | ((unsigned long long)f2b(v.y) << 16)
                        | ((unsigned long long)f2b(v.z) << 32)
                        | ((unsigned long long)f2b(v.w) << 48);
  ((unsigned long long*)out)[i] = pk;
}

// ---------------- transpose (+convert) to bf16, out[(col)*rows + row] ----------------
template<int FROM_F32>
__global__ __launch_bounds__(256) void transpose_to_bf16(const void* __restrict__ inv,
                                                         ushort_t* __restrict__ out,
                                                         int rows, int cols) {
  __shared__ __align__(16) ushort_t tile[64][65];
  const int t = threadIdx.x;
  const int br = blockIdx.y * 64, bc = blockIdx.x * 64;
#pragma unroll
  for (int i = 0; i < 16; i++) {
    int idx = i * 256 + t, r = idx >> 6, c = idx & 63;
    ushort_t v;
    if (FROM_F32) v = f2b(((const float*)inv)[(size_t)(br + r) * cols + bc + c]);
    else          v = ((const ushort_t*)inv)[(size_t)(br + r) * cols + bc + c];
    tile[r][c] = v;
  }
  __syncthreads();
#pragma unroll
  for (int i = 0; i < 16; i++) {
    int idx = i * 256 + t, r = idx >> 6, c = idx & 63;
    out[(size_t)(bc + r) * rows + br + c] = tile[c][r];
  }
}

// ---------------- RoPE cos/sin table: [T_][64] ----------------
__global__ __launch_bounds__(256) void rope_table(float* __restrict__ cs, float* __restrict__ sn) {
  int i = blockIdx.x * 256 + threadIdx.x;   // T_*64
  int tt = i >> 6, f = i & 63;
  float inv = powf(10000.0f, -(float)(2 * f) / 128.0f);
  float ang = (float)tt * inv;
  cs[i] = cosf(ang);
  sn[i] = sinf(ang);
}

// ---------------- RoPE apply in place on Q and K (bf16) ----------------
__global__ __launch_bounds__(256) void rope_apply(ushort_t* __restrict__ Q, ushort_t* __restrict__ K,
                                                  const float* __restrict__ cs,
                                                  const float* __restrict__ sn) {
  int i = blockIdx.x * 256 + threadIdx.x;   // M_ * 1024 pairs
  int row = i >> 10, p = i & 1023, f = p & 63, tt = row & (T_ - 1);
  float c = cs[(tt << 6) + f], s = sn[(tt << 6) + f];
  size_t idx = ((size_t)row << 11) + 2 * p;
  float qr = b2f(Q[idx]), qi = b2f(Q[idx + 1]);
  Q[idx]     = f2b(qr * c - qi * s);
  Q[idx + 1] = f2b(qr * s + qi * c);
  float kr = b2f(K[idx]), ki = b2f(K[idx + 1]);
  K[idx]     = f2b(kr * c - ki * s);
  K[idx + 1] = f2b(kr * s + ki * c);
}

// ---------------- GEMM: C[M,N] = A[M,K] (bf16, row-major) @ Bt[N,K]^T (bf16) ----------------
template<int OUTF32>
__global__ __launch_bounds__(256) void gemm_bt(const ushort_t* __restrict__ A,
                                               const ushort_t* __restrict__ Bt0,
                                               const ushort_t* __restrict__ Bt1,
                                               const ushort_t* __restrict__ Bt2,
                                               void* __restrict__ O0, void* __restrict__ O1,
                                               void* __restrict__ O2, int N, int K) {
  const int z = blockIdx.z;
  const ushort_t* Bt = (z == 0) ? Bt0 : (z == 1) ? Bt1 : Bt2;
  void* Ov = (z == 0) ? O0 : (z == 1) ? O1 : O2;
  const int t = threadIdx.x;
  const int lane = t & 63, wave = t >> 6;
  const int wr = wave >> 1, wc = wave & 1;
  const int lr = lane & 15, lg = lane >> 4;
  const int bm = blockIdx.y, bn = blockIdx.x;
  __shared__ __align__(16) ushort_t As[128 * 64];
  __shared__ __align__(16) ushort_t Bs[128 * 64];
  f32x4 acc[4][4] = {};
  const ushort_t* Ap = A + (size_t)bm * 128 * K;
  const ushort_t* Bp = Bt + (size_t)bn * 128 * K;
  for (int k0 = 0; k0 < K; k0 += 64) {
#pragma unroll
    for (int i = 0; i < 4; i++) {
      int chunk = i * 256 + t;
      int row = chunk >> 3, kc = chunk & 7;
      gload_lds16(Ap + (size_t)row * K + k0 + kc * 8, &As[(size_t)(i * 256 + wave * 64) * 8]);
      gload_lds16(Bp + (size_t)row * K + k0 + kc * 8, &Bs[(size_t)(i * 256 + wave * 64) * 8]);
    }
    __syncthreads();
#pragma unroll
    for (int kk = 0; kk < 64; kk += 32) {
      short8 af[4], bf[4];
#pragma unroll
      for (int i = 0; i < 4; i++) {
        af[i] = *(const short8*)&As[(wr * 64 + i * 16 + lr) * 64 + kk + lg * 8];
        bf[i] = *(const short8*)&Bs[(wc * 64 + i * 16 + lr) * 64 + kk + lg * 8];
      }
#pragma unroll
      for (int i = 0; i < 4; i++)
#pragma unroll
        for (int j = 0; j < 4; j++)
          acc[i][j] = __builtin_amdgcn_mfma_f32_16x16x32_bf16(af[i], bf[j], acc[i][j], 0, 0, 0);
    }
    __syncthreads();
  }
  const int row0 = bm * 128 + wr * 64 + lg * 4;
  const int col0 = bn * 128 + wc * 64 + lr;
  if (OUTF32) {
    float* O = (float*)Ov;
#pragma unroll
    for (int i = 0; i < 4; i++)
#pragma unroll
      for (int j = 0; j < 4; j++)
#pragma unroll
        for (int r = 0; r < 4; r++)
          O[(size_t)(row0 + i * 16 + r) * N + col0 + j * 16] = acc[i][j][r];
  } else {
    ushort_t* O = (ushort_t*)Ov;
#pragma unroll
    for (int i = 0; i < 4; i++)
#pragma unroll
      for (int j = 0; j < 4; j++)
#pragma unroll
        for (int r = 0; r < 4; r++)
          O[(size_t)(row0 + i * 16 + r) * N + col0 + j * 16] = f2b(acc[i][j][r]);
  }
}

// ---------------- Flash attention v2 ----------------
// Balanced 2-phase schedule: wave widx handles 16-row q-tiles {widx, 127-widx}
// sequentially -> uniform work (~32 KV64-steps per wave).
// grid: (16, B_*NH) with XCD swizzle on flat id; block 256 = 4 waves.
// Q,K: (B*T, C) bf16 (head h at col h*128). Vt: per (b,h): [128 d][T] bf16.
#define PSTR 72   // P LDS row stride (elems): 144B, 16B-aligned, spreads banks
__global__ __launch_bounds__(256, 2) void flash_attn2(const ushort_t* __restrict__ Q,
                                                      const ushort_t* __restrict__ K,
                                                      const ushort_t* __restrict__ Vt,
                                                      ushort_t* __restrict__ AO) {
  // XCD swizzle: 512 flat blocks, 8 XCDs, 64 blocks/XCD -> same-bh blocks colocate
  int orig = blockIdx.y * 16 + blockIdx.x;
  int wg = (orig & 7) * 64 + (orig >> 3);
  const int bh = wg >> 4, xblk = wg & 15;
  const int b = bh >> 4, h = bh & 15;
  const int wave = threadIdx.x >> 6, lane = threadIdx.x & 63;
  const int lr = lane & 15, lg = lane >> 4;
  const int widx = xblk * 4 + wave;   // 0..63 per bh
  const ushort_t* Qb = Q + (size_t)b * T_ * C_ + (size_t)h * HD;
  const ushort_t* Kb = K + (size_t)b * T_ * C_ + (size_t)h * HD;
  const ushort_t* Vb = Vt + (size_t)bh * (size_t)HD * T_;
  __shared__ __align__(16) ushort_t plds[4][16 * PSTR];
  ushort_t* myp = plds[wave];
  const float sc = 0.12754245f;  // log2(e)/sqrt(128)

  for (int ph = 0; ph < 2; ph++) {
    const int tile = ph ? (127 - widx) : widx;
    const int q0 = tile * 16;
    short8 qf[4];
#pragma unroll
    for (int di = 0; di < 4; di++)
      qf[di] = *(const short8*)&Qb[(size_t)(q0 + lr) * C_ + di * 32 + lg * 8];
    f32x4 o[8] = {};
    float m[4], l[4];
#pragma unroll
    for (int r = 0; r < 4; r++) { m[r] = -1e30f; l[r] = 0.f; }
    const int kend = q0 + 16;

    for (int k0 = 0; k0 < kend; k0 += 64) {
      const bool domask = (k0 + 63 > q0);
      f32x4 s[4] = {};
#pragma unroll
      for (int ct = 0; ct < 4; ct++) {
        if (k0 + ct * 16 <= q0 + 15) {   // tile not fully masked (wave-uniform)
          short8 kf[4];
#pragma unroll
          for (int di = 0; di < 4; di++)
            kf[di] = *(const short8*)&Kb[(size_t)(k0 + ct * 16 + lr) * C_ + di * 32 + lg * 8];
#pragma unroll
          for (int di = 0; di < 4; di++)
            s[ct] = __builtin_amdgcn_mfma_f32_16x16x32_bf16(qf[di], kf[di], s[ct], 0, 0, 0);
        }
      }
      const int qrow = q0 + lg * 4;
      float tm[4];
#pragma unroll
      for (int r = 0; r < 4; r++) {
        float v0 = s[0][r] * sc, v1 = s[1][r] * sc, v2 = s[2][r] * sc, v3 = s[3][r] * sc;
        if (domask) {
          if (k0 +      lr > qrow + r) v0 = -1e30f;
          if (k0 + 16 + lr > qrow + r) v1 = -1e30f;
          if (k0 + 32 + lr > qrow + r) v2 = -1e30f;
          if (k0 + 48 + lr > qrow + r) v3 = -1e30f;
        }
        s[0][r] = v0; s[1][r] = v1; s[2][r] = v2; s[3][r] = v3;
        tm[r] = fmaxf(fmaxf(v0, v1), fmaxf(v2, v3));
      }
#pragma unroll
      for (int off = 1; off < 16; off <<= 1)
#pragma unroll
        for (int r = 0; r < 4; r++)
          tm[r] = fmaxf(tm[r], __shfl_xor(tm[r], off, 64));
      float corr[4], rs[4];
#pragma unroll
      for (int r = 0; r < 4; r++) {
        float mn = fmaxf(m[r], tm[r]);
        corr[r] = exp2f(m[r] - mn);
        m[r] = mn;
      }
#pragma unroll
      for (int r = 0; r < 4; r++) {
        float p0 = exp2f(s[0][r] - m[r]);
        float p1 = exp2f(s[1][r] - m[r]);
        float p2 = exp2f(s[2][r] - m[r]);
        float p3 = exp2f(s[3][r] - m[r]);
        s[0][r] = p0; s[1][r] = p1; s[2][r] = p2; s[3][r] = p3;
        rs[r] = (p0 + p1) + (p2 + p3);
      }
#pragma unroll
      for (int off = 1; off < 16; off <<= 1)
#pragma unroll
        for (int r = 0; r < 4; r++)
          rs[r] += __shfl_xor(rs[r], off, 64);
#pragma unroll
      for (int r = 0; r < 4; r++) l[r] = l[r] * corr[r] + rs[r];
#pragma unroll
      for (int dc = 0; dc < 8; dc++)
#pragma unroll
        for (int r = 0; r < 4; r++) o[dc][r] *= corr[r];
      // P (C-layout) -> LDS [row][PSTR]
#pragma unroll
      for (int ct = 0; ct < 4; ct++)
#pragma unroll
        for (int r = 0; r < 4; r++)
          myp[(lg * 4 + r) * PSTR + ct * 16 + lr] = f2b(s[ct][r]);
      // PV
#pragma unroll
      for (int c = 0; c < 2; c++) {
        if (k0 + c * 32 <= q0 + 15) {  // chunk has any valid k (wave-uniform)
          short8 pa = *(const short8*)&myp[lr * PSTR + c * 32 + lg * 8];
#pragma unroll
          for (int dc = 0; dc < 8; dc++) {
            short8 vb = *(const short8*)&Vb[(size_t)(dc * 16 + lr) * T_ + k0 + c * 32 + lg * 8];
            o[dc] = __builtin_amdgcn_mfma_f32_16x16x32_bf16(pa, vb, o[dc], 0, 0, 0);
          }
        }
      }
    }
#pragma unroll
    for (int dc = 0; dc < 8; dc++)
#pragma unroll
      for (int r = 0; r < 4; r++) {
        float val = o[dc][r] / l[r];
        AO[(size_t)(b * T_ + q0 + lg * 4 + r) * C_ + h * HD + dc * 16 + lr] = f2b(val);
      }
  }
}

extern "C" void kernel_launch(void* const* d_in, const int* in_sizes, int n_in,
                              void* d_out, int out_size, void* d_ws, size_t ws_size,
                              hipStream_t stream) {
  const float* x  = (const float*)d_in[0];
  // d_in[1] = mask (causal tril) — implicit in the kernel
  const float* wq = (const float*)d_in[2];
  const float* wk = (const float*)d_in[3];
  const float* wv = (const float*)d_in[4];
  const float* wo = (const float*)d_in[5];

  char* ws = (char*)d_ws;
  size_t off = 0;
  auto alloc = [&](size_t bytes) { char* p = ws + off; off += (bytes + 255) & ~255ull; return p; };
  ushort_t* Qb  = (ushort_t*)alloc((size_t)M_ * C_ * 2);
  ushort_t* Kb  = (ushort_t*)alloc((size_t)M_ * C_ * 2);
  ushort_t* Vb  = (ushort_t*)alloc((size_t)M_ * C_ * 2);
  ushort_t* Vtb = (ushort_t*)alloc((size_t)M_ * C_ * 2);
  ushort_t* xb  = (ushort_t*)alloc((size_t)M_ * C_ * 2);
  ushort_t* AO  = xb;  // alias: xb dead after QKV GEMM
  ushort_t* wqt = (ushort_t*)alloc((size_t)C_ * C_ * 2);
  ushort_t* wkt = (ushort_t*)alloc((size_t)C_ * C_ * 2);
  ushort_t* wvt = (ushort_t*)alloc((size_t)C_ * C_ * 2);
  ushort_t* wot = (ushort_t*)alloc((size_t)C_ * C_ * 2);
  float* cs = (float*)alloc((size_t)T_ * 64 * 4);
  float* sn = (float*)alloc((size_t)T_ * 64 * 4);

  // 1. x -> bf16
  cvt_f32_bf16<<<(M_ * C_ / 4 + 255) / 256, 256, 0, stream>>>(x, xb, M_ * C_ / 4);
  // 2. weights -> bf16 transposed (N,K)
  dim3 tg(C_ / 64, C_ / 64);
  transpose_to_bf16<1><<<tg, 256, 0, stream>>>(wq, wqt, C_, C_);
  transpose_to_bf16<1><<<tg, 256, 0, stream>>>(wk, wkt, C_, C_);
  transpose_to_bf16<1><<<tg, 256, 0, stream>>>(wv, wvt, C_, C_);
  transpose_to_bf16<1><<<tg, 256, 0, stream>>>(wo, wot, C_, C_);
  // 3. RoPE tables
  rope_table<<<T_ * 64 / 256, 256, 0, stream>>>(cs, sn);
  // 4. QKV projections
  gemm_bt<0><<<dim3(C_ / 128, M_ / 128, 3), 256, 0, stream>>>(xb, wqt, wkt, wvt,
                                                              Qb, Kb, Vb, C_, C_);
  // 5. RoPE on Q, K
  rope_apply<<<M_ * 1024 / 256, 256, 0, stream>>>(Qb, Kb, cs, sn);
  // 6. V -> Vt per batch (2048x2048 transpose each)
  for (int b = 0; b < B_; b++)
    transpose_to_bf16<0><<<dim3(T_ / 64, T_ / 64), 256, 0, stream>>>(
        Vb + (size_t)b * T_ * C_, Vtb + (size_t)b * T_ * C_, T_, C_);
  // 7. flash attention (balanced 2-phase)
  flash_attn2<<<dim3(16, B_ * NH), 256, 0, stream>>>(Qb, Kb, Vtb, AO);
  // 8. output projection -> fp32 d_out
  gemm_bt<1><<<dim3(C_ / 128, M_ / 128, 1), 256, 0, stream>>>(AO, wot, wot, wot,
                                                              d_out, d_out, d_out, C_, C_);
  (void)in_sizes; (void)n_in; (void)out_size; (void)ws_size;
}

// Round 3
// 486.343 us; speedup vs baseline: 1.8114x; 1.3053x over previous
//
#include <hip/hip_runtime.h>
#include <stdint.h>

#define B_  2
#define T_  2048
#define C_  2048
#define NH  16
#define HD  128
#define M_  (B_*T_)   // 4096

typedef unsigned short ushort_t;
typedef unsigned int uint;
typedef __attribute__((ext_vector_type(8))) short short8;
typedef __attribute__((ext_vector_type(4))) float f32x4;
typedef __attribute__((ext_vector_type(16))) float f32x16;

#if __has_builtin(__builtin_amdgcn_exp2f)
#define EXP2 __builtin_amdgcn_exp2f
#else
#define EXP2 exp2f
#endif

__device__ inline ushort_t f2b(float f) {
  union { float f; unsigned u; } x; x.f = f;
  unsigned r = (x.u + 0x7fffu + ((x.u >> 16) & 1u)) >> 16;
  return (ushort_t)r;
}
__device__ inline float b2f(ushort_t b) {
  union { unsigned u; float f; } x; x.u = ((unsigned)b) << 16;
  return x.f;
}
__device__ inline uint cvtpk(float lo, float hi) {
  uint d;
  asm("v_cvt_pk_bf16_f32 %0, %1, %2" : "=v"(d) : "v"(lo), "v"(hi));
  return d;
}
__device__ inline void pl32swap(uint& a, uint& b) {
  asm volatile("v_permlane32_swap_b32 %0, %1" : "+v"(a), "+v"(b));
}
__device__ inline void gload_lds16(const void* g, void* l) {
  __builtin_amdgcn_global_load_lds((const __attribute__((address_space(1))) void*)g,
                                   (__attribute__((address_space(3))) void*)l, 16, 0, 0);
}

// ---------------- x fp32 -> bf16 ----------------
__global__ __launch_bounds__(256) void cvt_f32_bf16(const float* __restrict__ in,
                                                    ushort_t* __restrict__ out, int n4) {
  int i = blockIdx.x * 256 + threadIdx.x;
  if (i >= n4) return;
  float4 v = ((const float4*)in)[i];
  unsigned long long pk = (unsigned long long)f2b(v.x)
                        | ((unsigned long long)f2b(v.y) << 16)
                        | ((unsigned long long)f2b(v.z) << 32)
                        | ((unsigned long long)f2b(v.w) << 48);
  ((unsigned long long*)out)[i] = pk;
}

// ---------------- transpose (+convert) to bf16, out[(col)*rows + row], vector IO ----------------
template<int FROM_F32>
__global__ __launch_bounds__(256) void transpose_to_bf16(const void* __restrict__ inv,
                                                         ushort_t* __restrict__ out,
                                                         int rows, int cols) {
  __shared__ __align__(16) ushort_t tile[64][72];
  const int t = threadIdx.x;
  const int br = blockIdx.y * 64, bc = blockIdx.x * 64;
  if (FROM_F32) {
    const float* in = (const float*)inv;
    const int vc = t & 15, r0 = t >> 4;   // 4-col groups
#pragma unroll
    for (int i = 0; i < 4; i++) {
      int row = r0 + 16 * i;
      float4 v = *(const float4*)&in[(size_t)(br + row) * cols + bc + vc * 4];
      tile[row][vc * 4 + 0] = f2b(v.x);
      tile[row][vc * 4 + 1] = f2b(v.y);
      tile[row][vc * 4 + 2] = f2b(v.z);
      tile[row][vc * 4 + 3] = f2b(v.w);
    }
  } else {
    const ushort_t* in = (const ushort_t*)inv;
    const int vc = t & 7, r0 = t >> 3;    // 8-col groups
#pragma unroll
    for (int i = 0; i < 2; i++) {
      int row = r0 + 32 * i;
      short8 v = *(const short8*)&in[(size_t)(br + row) * cols + bc + vc * 8];
#pragma unroll
      for (int j = 0; j < 8; j++) tile[row][vc * 8 + j] = (ushort_t)v[j];
    }
  }
  __syncthreads();
  const int oc = t >> 2;                   // output row = orig col, 0..63
#pragma unroll
  for (int s2 = 0; s2 < 2; s2++) {
    int seg = (t & 3) + 4 * s2;            // 8-orig-row group
    short8 w;
#pragma unroll
    for (int j = 0; j < 8; j++) w[j] = (short)tile[seg * 8 + j][oc];
    *(short8*)&out[(size_t)(bc + oc) * rows + br + seg * 8] = w;
  }
}

// ---------------- RoPE cos/sin table: [T_][64] ----------------
__global__ __launch_bounds__(256) void rope_table(float* __restrict__ cs, float* __restrict__ sn) {
  int i = blockIdx.x * 256 + threadIdx.x;   // T_*64
  int tt = i >> 6, f = i & 63;
  float inv = powf(10000.0f, -(float)(2 * f) / 128.0f);
  float ang = (float)tt * inv;
  cs[i] = cosf(ang);
  sn[i] = sinf(ang);
}

// ---------------- RoPE apply in place on Q and K (bf16), vectorized ----------------
__global__ __launch_bounds__(256) void rope_apply(ushort_t* __restrict__ Q, ushort_t* __restrict__ K,
                                                  const float* __restrict__ cs,
                                                  const float* __restrict__ sn) {
  int i = blockIdx.x * 256 + threadIdx.x;   // M_*C_/8 groups of 8 elems (4 pairs)
  int row = i >> 8, g = i & 255;
  int tt = row & (T_ - 1);
  int fb = (g * 4) & 63;
  f32x4 cv = *(const f32x4*)&cs[(tt << 6) + fb];
  f32x4 sv = *(const f32x4*)&sn[(tt << 6) + fb];
  size_t idx = ((size_t)row << 11) + (size_t)g * 8;
  short8 q = *(const short8*)&Q[idx];
  short8 k = *(const short8*)&K[idx];
#pragma unroll
  for (int j = 0; j < 4; j++) {
    float c = cv[j], s = sv[j];
    float qr = b2f((ushort_t)q[2 * j]), qi = b2f((ushort_t)q[2 * j + 1]);
    q[2 * j]     = (short)f2b(qr * c - qi * s);
    q[2 * j + 1] = (short)f2b(qr * s + qi * c);
    float kr = b2f((ushort_t)k[2 * j]), ki = b2f((ushort_t)k[2 * j + 1]);
    k[2 * j]     = (short)f2b(kr * c - ki * s);
    k[2 * j + 1] = (short)f2b(kr * s + ki * c);
  }
  *(short8*)&Q[idx] = q;
  *(short8*)&K[idx] = k;
}

// ---------------- GEMM: C[M,N] = A[M,K] (bf16, row-major) @ Bt[N,K]^T (bf16) ----------------
template<int OUTF32>
__global__ __launch_bounds__(256) void gemm_bt(const ushort_t* __restrict__ A,
                                               const ushort_t* __restrict__ Bt0,
                                               const ushort_t* __restrict__ Bt1,
                                               const ushort_t* __restrict__ Bt2,
                                               void* __restrict__ O0, void* __restrict__ O1,
                                               void* __restrict__ O2, int N, int K) {
  const int z = blockIdx.z;
  const ushort_t* Bt = (z == 0) ? Bt0 : (z == 1) ? Bt1 : Bt2;
  void* Ov = (z == 0) ? O0 : (z == 1) ? O1 : O2;
  const int t = threadIdx.x;
  const int lane = t & 63, wave = t >> 6;
  const int wr = wave >> 1, wc = wave & 1;
  const int lr = lane & 15, lg = lane >> 4;
  const int bm = blockIdx.y, bn = blockIdx.x;
  __shared__ __align__(16) ushort_t As[128 * 64];
  __shared__ __align__(16) ushort_t Bs[128 * 64];
  f32x4 acc[4][4] = {};
  const ushort_t* Ap = A + (size_t)bm * 128 * K;
  const ushort_t* Bp = Bt + (size_t)bn * 128 * K;
  for (int k0 = 0; k0 < K; k0 += 64) {
#pragma unroll
    for (int i = 0; i < 4; i++) {
      int chunk = i * 256 + t;
      int row = chunk >> 3, kc = chunk & 7;
      gload_lds16(Ap + (size_t)row * K + k0 + kc * 8, &As[(size_t)(i * 256 + wave * 64) * 8]);
      gload_lds16(Bp + (size_t)row * K + k0 + kc * 8, &Bs[(size_t)(i * 256 + wave * 64) * 8]);
    }
    __syncthreads();
#pragma unroll
    for (int kk = 0; kk < 64; kk += 32) {
      short8 af[4], bf[4];
#pragma unroll
      for (int i = 0; i < 4; i++) {
        af[i] = *(const short8*)&As[(wr * 64 + i * 16 + lr) * 64 + kk + lg * 8];
        bf[i] = *(const short8*)&Bs[(wc * 64 + i * 16 + lr) * 64 + kk + lg * 8];
      }
#pragma unroll
      for (int i = 0; i < 4; i++)
#pragma unroll
        for (int j = 0; j < 4; j++)
          acc[i][j] = __builtin_amdgcn_mfma_f32_16x16x32_bf16(af[i], bf[j], acc[i][j], 0, 0, 0);
    }
    __syncthreads();
  }
  const int row0 = bm * 128 + wr * 64 + lg * 4;
  const int col0 = bn * 128 + wc * 64 + lr;
  if (OUTF32) {
    float* O = (float*)Ov;
#pragma unroll
    for (int i = 0; i < 4; i++)
#pragma unroll
      for (int j = 0; j < 4; j++)
#pragma unroll
        for (int r = 0; r < 4; r++)
          O[(size_t)(row0 + i * 16 + r) * N + col0 + j * 16] = acc[i][j][r];
  } else {
    ushort_t* O = (ushort_t*)Ov;
#pragma unroll
    for (int i = 0; i < 4; i++)
#pragma unroll
      for (int j = 0; j < 4; j++)
#pragma unroll
        for (int r = 0; r < 4; r++)
          O[(size_t)(row0 + i * 16 + r) * N + col0 + j * 16] = f2b(acc[i][j][r]);
  }
}

// ---------------- Flash attention v3: swapped-QK 32x32, in-register softmax ----------------
// 1024 blocks x 64 threads (1 wave). Wave handles q-tile pair {widx, 63-widx} (32 rows each)
// -> uniform 65 KV-32 steps. S^T = mfma32x32x16(K, Q); lane owns q=lane&31, 16 of 32 k-scores;
// softmax in-register + one shfl_xor(32). P->A-frag via cvt_pk_bf16 + permlane32_swap (T12).
// O^T accumulated via mfma(V^T, P^T); Vt layout [d][t] per (b,h).
__global__ __launch_bounds__(64) void flash_attn3(const ushort_t* __restrict__ Q,
                                                  const ushort_t* __restrict__ K,
                                                  const ushort_t* __restrict__ Vt,
                                                  ushort_t* __restrict__ AO) {
  // XCD swizzle: 1024 blocks -> 128 consecutive per XCD (4 bh's K/V colocate in L2)
  int flat = blockIdx.x;
  int swz = (flat & 7) * 128 + (flat >> 3);
  const int bh = swz >> 5, widx = swz & 31;
  const int b = bh >> 4, h = bh & 15;
  const int lane = threadIdx.x & 63;
  const int col = lane & 31, hi = lane >> 5, hioff = 4 * hi;
  const ushort_t* Qb = Q + (size_t)b * T_ * C_ + (size_t)h * HD;
  const ushort_t* Kb = K + (size_t)b * T_ * C_ + (size_t)h * HD;
  const ushort_t* Vb = Vt + (size_t)bh * (size_t)HD * T_;
  const float sc = 0.12754245f;  // log2(e)/sqrt(128)

#pragma unroll 1
  for (int ph = 0; ph < 2; ph++) {
    const int tile = ph ? (63 - widx) : widx;
    const int q0 = tile * 32;
    const int qcol = q0 + col;
    // Q B-fragments: lane holds Q[q0+col][db*16 + hi*8 + e]
    short8 qf[8];
#pragma unroll
    for (int db = 0; db < 8; db++)
      qf[db] = *(const short8*)&Qb[(size_t)qcol * C_ + db * 16 + hi * 8];

    f32x16 o0 = {}, o1 = {}, o2 = {}, o3 = {};
    float m = -1e30f, l = 0.f;

    // preload K for k0=0
    short8 kf[8];
#pragma unroll
    for (int db = 0; db < 8; db++)
      kf[db] = *(const short8*)&Kb[(size_t)col * C_ + db * 16 + hi * 8];

#pragma unroll 1
    for (int k0 = 0; k0 <= q0; k0 += 32) {
      // S^T[k][q] over d=128
      f32x16 s = {};
#pragma unroll
      for (int db = 0; db < 8; db++)
        s = __builtin_amdgcn_mfma_f32_32x32x16_bf16(kf[db], qf[db], s, 0, 0, 0);
      // prefetch next K tile
      if (k0 + 32 <= q0) {
#pragma unroll
        for (int db = 0; db < 8; db++)
          kf[db] = *(const short8*)&Kb[(size_t)(k0 + 32 + col) * C_ + db * 16 + hi * 8];
      }
      // V loads early (used after softmax)
      short8 va[4][2];
#pragma unroll
      for (int dblk = 0; dblk < 4; dblk++)
#pragma unroll
        for (int j = 0; j < 2; j++)
          va[dblk][j] = *(const short8*)&Vb[(size_t)(dblk * 32 + col) * T_ + k0 + j * 16 + hi * 8];

      // scale + causal mask. k-row of reg r: k0 + (r&3)+8*(r>>2)+4*hi
      const bool domask = (k0 + 31 > q0);
      if (domask) {
#pragma unroll
        for (int r = 0; r < 16; r++) {
          int krow = k0 + ((r & 3) + 8 * (r >> 2)) + hioff;
          float v = s[r] * sc;
          s[r] = (krow > qcol) ? -1e30f : v;
        }
      } else {
#pragma unroll
        for (int r = 0; r < 16; r++) s[r] = s[r] * sc;
      }
      // row max: 15 in-register + 1 xor32
      float tm = s[0];
#pragma unroll
      for (int r = 1; r < 16; r++) tm = fmaxf(tm, s[r]);
      tm = fmaxf(tm, __shfl_xor(tm, 32, 64));
      // online-softmax with defer-max (T13)
      if (!__all(tm <= m + 8.0f)) {
        float mn = fmaxf(m, tm);
        float corr = EXP2(m - mn);
        m = mn;
        l *= corr;
#pragma unroll
        for (int r = 0; r < 16; r++) { o0[r] *= corr; o1[r] *= corr; o2[r] *= corr; o3[r] *= corr; }
      }
#pragma unroll
      for (int r = 0; r < 16; r++) s[r] = EXP2(s[r] - m);
      float rs = s[0];
#pragma unroll
      for (int r = 1; r < 16; r++) rs += s[r];
      rs += __shfl_xor(rs, 32, 64);
      l += rs;
      // P^T B-frags via cvt_pk + permlane32_swap (T12 derivation)
      uint c0 = cvtpk(s[0], s[1]),  c1 = cvtpk(s[2], s[3]);
      uint c2 = cvtpk(s[4], s[5]),  c3 = cvtpk(s[6], s[7]);
      uint c4 = cvtpk(s[8], s[9]),  c5 = cvtpk(s[10], s[11]);
      uint c6 = cvtpk(s[12], s[13]), c7 = cvtpk(s[14], s[15]);
      pl32swap(c0, c2); pl32swap(c1, c3);
      pl32swap(c4, c6); pl32swap(c5, c7);
      union { uint u[4]; short8 v; } pb0, pb1;
      pb0.u[0] = c0; pb0.u[1] = c1; pb0.u[2] = c2; pb0.u[3] = c3;
      pb1.u[0] = c4; pb1.u[1] = c5; pb1.u[2] = c6; pb1.u[3] = c7;
      // PV: O^T[d][q] += V^T[d][k] P^T[k][q]
      o0 = __builtin_amdgcn_mfma_f32_32x32x16_bf16(va[0][0], pb0.v, o0, 0, 0, 0);
      o1 = __builtin_amdgcn_mfma_f32_32x32x16_bf16(va[1][0], pb0.v, o1, 0, 0, 0);
      o2 = __builtin_amdgcn_mfma_f32_32x32x16_bf16(va[2][0], pb0.v, o2, 0, 0, 0);
      o3 = __builtin_amdgcn_mfma_f32_32x32x16_bf16(va[3][0], pb0.v, o3, 0, 0, 0);
      o0 = __builtin_amdgcn_mfma_f32_32x32x16_bf16(va[0][1], pb1.v, o0, 0, 0, 0);
      o1 = __builtin_amdgcn_mfma_f32_32x32x16_bf16(va[1][1], pb1.v, o1, 0, 0, 0);
      o2 = __builtin_amdgcn_mfma_f32_32x32x16_bf16(va[2][1], pb1.v, o2, 0, 0, 0);
      o3 = __builtin_amdgcn_mfma_f32_32x32x16_bf16(va[3][1], pb1.v, o3, 0, 0, 0);
    }
    // epilogue: O^T C-layout: col=q, row(within dblk) = (r&3)+8*(r>>2)+4*hi
    float inv = 1.0f / l;
    size_t rowbase = (size_t)(b * T_ + qcol) * C_ + h * HD;
#pragma unroll
    for (int r = 0; r < 16; r++) {
      int d = (r & 3) + 8 * (r >> 2) + hioff;
      AO[rowbase + d]      = f2b(o0[r] * inv);
      AO[rowbase + 32 + d] = f2b(o1[r] * inv);
      AO[rowbase + 64 + d] = f2b(o2[r] * inv);
      AO[rowbase + 96 + d] = f2b(o3[r] * inv);
    }
  }
}

extern "C" void kernel_launch(void* const* d_in, const int* in_sizes, int n_in,
                              void* d_out, int out_size, void* d_ws, size_t ws_size,
                              hipStream_t stream) {
  const float* x  = (const float*)d_in[0];
  // d_in[1] = mask (causal tril) — implicit in the kernel
  const float* wq = (const float*)d_in[2];
  const float* wk = (const float*)d_in[3];
  const float* wv = (const float*)d_in[4];
  const float* wo = (const float*)d_in[5];

  char* ws = (char*)d_ws;
  size_t off = 0;
  auto alloc = [&](size_t bytes) { char* p = ws + off; off += (bytes + 255) & ~255ull; return p; };
  ushort_t* Qb  = (ushort_t*)alloc((size_t)M_ * C_ * 2);
  ushort_t* Kb  = (ushort_t*)alloc((size_t)M_ * C_ * 2);
  ushort_t* Vb  = (ushort_t*)alloc((size_t)M_ * C_ * 2);
  ushort_t* Vtb = (ushort_t*)alloc((size_t)M_ * C_ * 2);
  ushort_t* xb  = (ushort_t*)alloc((size_t)M_ * C_ * 2);
  ushort_t* AO  = xb;  // alias: xb dead after QKV GEMM
  ushort_t* wqt = (ushort_t*)alloc((size_t)C_ * C_ * 2);
  ushort_t* wkt = (ushort_t*)alloc((size_t)C_ * C_ * 2);
  ushort_t* wvt = (ushort_t*)alloc((size_t)C_ * C_ * 2);
  ushort_t* wot = (ushort_t*)alloc((size_t)C_ * C_ * 2);
  float* cs = (float*)alloc((size_t)T_ * 64 * 4);
  float* sn = (float*)alloc((size_t)T_ * 64 * 4);

  // 1. x -> bf16
  cvt_f32_bf16<<<(M_ * C_ / 4 + 255) / 256, 256, 0, stream>>>(x, xb, M_ * C_ / 4);
  // 2. weights -> bf16 transposed (N,K)
  dim3 tg(C_ / 64, C_ / 64);
  transpose_to_bf16<1><<<tg, 256, 0, stream>>>(wq, wqt, C_, C_);
  transpose_to_bf16<1><<<tg, 256, 0, stream>>>(wk, wkt, C_, C_);
  transpose_to_bf16<1><<<tg, 256, 0, stream>>>(wv, wvt, C_, C_);
  transpose_to_bf16<1><<<tg, 256, 0, stream>>>(wo, wot, C_, C_);
  // 3. RoPE tables
  rope_table<<<T_ * 64 / 256, 256, 0, stream>>>(cs, sn);
  // 4. QKV projections
  gemm_bt<0><<<dim3(C_ / 128, M_ / 128, 3), 256, 0, stream>>>(xb, wqt, wkt, wvt,
                                                              Qb, Kb, Vb, C_, C_);
  // 5. RoPE on Q, K
  rope_apply<<<M_ * C_ / 8 / 256, 256, 0, stream>>>(Qb, Kb, cs, sn);
  // 6. V -> Vt per batch (2048x2048 transpose each)
  for (int b = 0; b < B_; b++)
    transpose_to_bf16<0><<<dim3(T_ / 64, T_ / 64), 256, 0, stream>>>(
        Vb + (size_t)b * T_ * C_, Vtb + (size_t)b * T_ * C_, T_, C_);
  // 7. flash attention v3 (swapped-QK 32x32, in-register softmax)
  flash_attn3<<<dim3(B_ * NH * 32), 64, 0, stream>>>(Qb, Kb, Vtb, AO);
  // 8. output projection -> fp32 d_out
  gemm_bt<1><<<dim3(C_ / 128, M_ / 128, 1), 256, 0, stream>>>(AO, wot, wot, wot,
                                                              d_out, d_out, d_out, C_, C_);
  (void)in_sizes; (void)n_in; (void)out_size; (void)ws_size;
}

// Round 4
// 481.357 us; speedup vs baseline: 1.8302x; 1.0104x over previous
//
#include <hip/hip_runtime.h>
#include <stdint.h>

#define B_  2
#define T_  2048
#define C_  2048
#define NH  16
#define HD  128
#define M_  (B_*T_)   // 4096

typedef unsigned short ushort_t;
typedef unsigned int uint;
typedef __attribute__((ext_vector_type(8))) short short8;
typedef __attribute__((ext_vector_type(4))) float f32x4;
typedef __attribute__((ext_vector_type(16))) float f32x16;

#if __has_builtin(__builtin_amdgcn_exp2f)
#define EXP2 __builtin_amdgcn_exp2f
#else
#define EXP2 exp2f
#endif

__device__ inline ushort_t f2b(float f) {
  union { float f; unsigned u; } x; x.f = f;
  unsigned r = (x.u + 0x7fffu + ((x.u >> 16) & 1u)) >> 16;
  return (ushort_t)r;
}
__device__ inline float b2f(ushort_t b) {
  union { unsigned u; float f; } x; x.u = ((unsigned)b) << 16;
  return x.f;
}
__device__ inline uint cvtpk(float lo, float hi) {
  uint d;
  asm("v_cvt_pk_bf16_f32 %0, %1, %2" : "=v"(d) : "v"(lo), "v"(hi));
  return d;
}
__device__ inline void pl32swap(uint& a, uint& b) {
  asm volatile("v_permlane32_swap_b32 %0, %1" : "+v"(a), "+v"(b));
}
__device__ inline void gload_lds16(const void* g, void* l) {
  __builtin_amdgcn_global_load_lds((const __attribute__((address_space(1))) void*)g,
                                   (__attribute__((address_space(3))) void*)l, 16, 0, 0);
}

// ---------------- x fp32 -> bf16 ----------------
__global__ __launch_bounds__(256) void cvt_f32_bf16(const float* __restrict__ in,
                                                    ushort_t* __restrict__ out, int n4) {
  int i = blockIdx.x * 256 + threadIdx.x;
  if (i >= n4) return;
  float4 v = ((const float4*)in)[i];
  unsigned long long pk = (unsigned long long)f2b(v.x)
                        | ((unsigned long long)f2b(v.y) << 16)
                        | ((unsigned long long)f2b(v.z) << 32)
                        | ((unsigned long long)f2b(v.w) << 48);
  ((unsigned long long*)out)[i] = pk;
}

// ---------------- transpose (+convert) to bf16, out[(col)*rows + row], vector IO ----------------
template<int FROM_F32>
__global__ __launch_bounds__(256) void transpose_to_bf16(const void* __restrict__ inv,
                                                         ushort_t* __restrict__ out,
                                                         int rows, int cols) {
  __shared__ __align__(16) ushort_t tile[64][72];
  const int t = threadIdx.x;
  const int br = blockIdx.y * 64, bc = blockIdx.x * 64;
  if (FROM_F32) {
    const float* in = (const float*)inv;
    const int vc = t & 15, r0 = t >> 4;   // 4-col groups
#pragma unroll
    for (int i = 0; i < 4; i++) {
      int row = r0 + 16 * i;
      float4 v = *(const float4*)&in[(size_t)(br + row) * cols + bc + vc * 4];
      tile[row][vc * 4 + 0] = f2b(v.x);
      tile[row][vc * 4 + 1] = f2b(v.y);
      tile[row][vc * 4 + 2] = f2b(v.z);
      tile[row][vc * 4 + 3] = f2b(v.w);
    }
  } else {
    const ushort_t* in = (const ushort_t*)inv;
    const int vc = t & 7, r0 = t >> 3;    // 8-col groups
#pragma unroll
    for (int i = 0; i < 2; i++) {
      int row = r0 + 32 * i;
      short8 v = *(const short8*)&in[(size_t)(br + row) * cols + bc + vc * 8];
#pragma unroll
      for (int j = 0; j < 8; j++) tile[row][vc * 8 + j] = (ushort_t)v[j];
    }
  }
  __syncthreads();
  const int oc = t >> 2;                   // output row = orig col, 0..63
#pragma unroll
  for (int s2 = 0; s2 < 2; s2++) {
    int seg = (t & 3) + 4 * s2;            // 8-orig-row group
    short8 w;
#pragma unroll
    for (int j = 0; j < 8; j++) w[j] = (short)tile[seg * 8 + j][oc];
    *(short8*)&out[(size_t)(bc + oc) * rows + br + seg * 8] = w;
  }
}

// ---------------- RoPE cos/sin table: [T_][64] ----------------
__global__ __launch_bounds__(256) void rope_table(float* __restrict__ cs, float* __restrict__ sn) {
  int i = blockIdx.x * 256 + threadIdx.x;   // T_*64
  int tt = i >> 6, f = i & 63;
  float inv = powf(10000.0f, -(float)(2 * f) / 128.0f);
  float ang = (float)tt * inv;
  cs[i] = cosf(ang);
  sn[i] = sinf(ang);
}

// ---------------- RoPE apply in place on Q and K (bf16), vectorized ----------------
__global__ __launch_bounds__(256) void rope_apply(ushort_t* __restrict__ Q, ushort_t* __restrict__ K,
                                                  const float* __restrict__ cs,
                                                  const float* __restrict__ sn) {
  int i = blockIdx.x * 256 + threadIdx.x;   // M_*C_/8 groups of 8 elems (4 pairs)
  int row = i >> 8, g = i & 255;
  int tt = row & (T_ - 1);
  int fb = (g * 4) & 63;
  f32x4 cv = *(const f32x4*)&cs[(tt << 6) + fb];
  f32x4 sv = *(const f32x4*)&sn[(tt << 6) + fb];
  size_t idx = ((size_t)row << 11) + (size_t)g * 8;
  short8 q = *(const short8*)&Q[idx];
  short8 k = *(const short8*)&K[idx];
#pragma unroll
  for (int j = 0; j < 4; j++) {
    float c = cv[j], s = sv[j];
    float qr = b2f((ushort_t)q[2 * j]), qi = b2f((ushort_t)q[2 * j + 1]);
    q[2 * j]     = (short)f2b(qr * c - qi * s);
    q[2 * j + 1] = (short)f2b(qr * s + qi * c);
    float kr = b2f((ushort_t)k[2 * j]), ki = b2f((ushort_t)k[2 * j + 1]);
    k[2 * j]     = (short)f2b(kr * c - ki * s);
    k[2 * j + 1] = (short)f2b(kr * s + ki * c);
  }
  *(short8*)&Q[idx] = q;
  *(short8*)&K[idx] = k;
}

// ---------------- GEMM v2: 256x256 tile, BK=64, 8 waves, 2-buffer counted-vmcnt pipeline ----------------
// C[M,N] = A[M,K] @ Bt[N,K]^T, bf16 in, bf16/f32 out.
// LDS (dynamic 128 KiB): buf{0,1} x { A[256][64], B[256][64] } with 16B-chunk XOR swizzle
// (chunk ^= row&7) applied on the GLOBAL source (linear LDS dest, per gload_lds constraint)
// and on the ds_read address. Pipeline: stage t+1 -> vmcnt(8) (waits tile t only) -> barrier
// -> 64 MFMA/wave. Loads stay in flight across barriers (T3/T4); setprio around MFMA (T5).
template<int OUTF32>
__global__ __launch_bounds__(512, 2) void gemm_bt256(const ushort_t* __restrict__ A,
                                                     const ushort_t* __restrict__ Bt0,
                                                     const ushort_t* __restrict__ Bt1,
                                                     const ushort_t* __restrict__ Bt2,
                                                     void* __restrict__ O0, void* __restrict__ O1,
                                                     void* __restrict__ O2, int N, int K) {
  extern __shared__ __align__(16) ushort_t lds[];   // 65536 elems = 128 KiB
  const int z = blockIdx.z;
  const ushort_t* Bt = (z == 0) ? Bt0 : (z == 1) ? Bt1 : Bt2;
  void* Ov = (z == 0) ? O0 : (z == 1) ? O1 : O2;
  const int tid = threadIdx.x;
  const int lane = tid & 63, wave = tid >> 6;
  const int lr = lane & 15, lg = lane >> 4;
  const int wm = wave >> 2, wn = wave & 3;          // 2 M-waves x 4 N-waves
  const int swz = lr & 7;
  const int bm = blockIdx.y, bn = blockIdx.x;
  const ushort_t* Ap = A + (size_t)bm * 256 * K;
  const ushort_t* Bp = Bt + (size_t)bn * 256 * K;
  const int NT = K >> 6;

  f32x4 acc[8][4] = {};

  // stage one K-tile (A 32KB + B 32KB) into lds[base..base+32768)
  auto stage8 = [&](int k0, int base) {
#pragma unroll
    for (int i = 0; i < 4; i++) {
      int idx = i * 512 + wave * 64 + lane;          // chunk index 0..2047
      int row = idx >> 3;
      int c = (idx & 7) ^ (row & 7);                 // inverse-swizzled source chunk
      gload_lds16(Ap + (size_t)row * K + k0 + c * 8,
                  &lds[(size_t)base + (size_t)(i * 512 + wave * 64) * 8]);
    }
#pragma unroll
    for (int i = 0; i < 4; i++) {
      int idx = i * 512 + wave * 64 + lane;
      int row = idx >> 3;
      int c = (idx & 7) ^ (row & 7);
      gload_lds16(Bp + (size_t)row * K + k0 + c * 8,
                  &lds[(size_t)base + 16384 + (size_t)(i * 512 + wave * 64) * 8]);
    }
  };

  stage8(0, 0);   // prologue: tile 0 -> buf0

  for (int t = 0; t < NT; t++) {
    __builtin_amdgcn_s_barrier();                    // close prev iter's reads
    if (t + 1 < NT) {
      stage8((t + 1) << 6, ((t + 1) & 1) * 32768);   // tile t+1 -> other buffer
      asm volatile("s_waitcnt vmcnt(8)" ::: "memory");   // tile t landed; t+1 in flight
    } else {
      asm volatile("s_waitcnt vmcnt(0)" ::: "memory");
    }
    __builtin_amdgcn_s_barrier();                    // all waves see tile t
    const int abase = (t & 1) * 32768, bbase = abase + 16384;
    __builtin_amdgcn_s_setprio(1);
#pragma unroll
    for (int kk = 0; kk < 2; kk++) {
      short8 af[8], bf[4];
#pragma unroll
      for (int mf = 0; mf < 8; mf++)
        af[mf] = *(const short8*)&lds[abase + (wm * 128 + mf * 16 + lr) * 64 +
                                      (((kk * 4) + lg) ^ swz) * 8];
#pragma unroll
      for (int nf = 0; nf < 4; nf++)
        bf[nf] = *(const short8*)&lds[bbase + (wn * 64 + nf * 16 + lr) * 64 +
                                      (((kk * 4) + lg) ^ swz) * 8];
#pragma unroll
      for (int mf = 0; mf < 8; mf++)
#pragma unroll
        for (int nf = 0; nf < 4; nf++)
          acc[mf][nf] = __builtin_amdgcn_mfma_f32_16x16x32_bf16(af[mf], bf[nf], acc[mf][nf], 0, 0, 0);
    }
    __builtin_amdgcn_s_setprio(0);
  }

  const int row0 = bm * 256 + wm * 128 + lg * 4;
  const int col0 = bn * 256 + wn * 64 + lr;
  if (OUTF32) {
    float* O = (float*)Ov;
#pragma unroll
    for (int mf = 0; mf < 8; mf++)
#pragma unroll
      for (int nf = 0; nf < 4; nf++)
#pragma unroll
        for (int r = 0; r < 4; r++)
          O[(size_t)(row0 + mf * 16 + r) * N + col0 + nf * 16] = acc[mf][nf][r];
  } else {
    ushort_t* O = (ushort_t*)Ov;
#pragma unroll
    for (int mf = 0; mf < 8; mf++)
#pragma unroll
      for (int nf = 0; nf < 4; nf++)
#pragma unroll
        for (int r = 0; r < 4; r++)
          O[(size_t)(row0 + mf * 16 + r) * N + col0 + nf * 16] = f2b(acc[mf][nf][r]);
  }
}

// ---------------- Flash attention v3: swapped-QK 32x32, in-register softmax ----------------
// 1024 blocks x 64 threads (1 wave). Wave handles q-tile pair {widx, 63-widx} (32 rows each)
// -> uniform 65 KV-32 steps. S^T = mfma32x32x16(K, Q); lane owns q=lane&31, 16 of 32 k-scores;
// softmax in-register + one shfl_xor(32). P->A-frag via cvt_pk_bf16 + permlane32_swap (T12).
// O^T accumulated via mfma(V^T, P^T); Vt layout [d][t] per (b,h).
__global__ __launch_bounds__(64) void flash_attn3(const ushort_t* __restrict__ Q,
                                                  const ushort_t* __restrict__ K,
                                                  const ushort_t* __restrict__ Vt,
                                                  ushort_t* __restrict__ AO) {
  // XCD swizzle: 1024 blocks -> 128 consecutive per XCD (4 bh's K/V colocate in L2)
  int flat = blockIdx.x;
  int swz = (flat & 7) * 128 + (flat >> 3);
  const int bh = swz >> 5, widx = swz & 31;
  const int b = bh >> 4, h = bh & 15;
  const int lane = threadIdx.x & 63;
  const int col = lane & 31, hi = lane >> 5, hioff = 4 * hi;
  const ushort_t* Qb = Q + (size_t)b * T_ * C_ + (size_t)h * HD;
  const ushort_t* Kb = K + (size_t)b * T_ * C_ + (size_t)h * HD;
  const ushort_t* Vb = Vt + (size_t)bh * (size_t)HD * T_;
  const float sc = 0.12754245f;  // log2(e)/sqrt(128)

#pragma unroll 1
  for (int ph = 0; ph < 2; ph++) {
    const int tile = ph ? (63 - widx) : widx;
    const int q0 = tile * 32;
    const int qcol = q0 + col;
    // Q B-fragments: lane holds Q[q0+col][db*16 + hi*8 + e]
    short8 qf[8];
#pragma unroll
    for (int db = 0; db < 8; db++)
      qf[db] = *(const short8*)&Qb[(size_t)qcol * C_ + db * 16 + hi * 8];

    f32x16 o0 = {}, o1 = {}, o2 = {}, o3 = {};
    float m = -1e30f, l = 0.f;

    // preload K for k0=0
    short8 kf[8];
#pragma unroll
    for (int db = 0; db < 8; db++)
      kf[db] = *(const short8*)&Kb[(size_t)col * C_ + db * 16 + hi * 8];

#pragma unroll 1
    for (int k0 = 0; k0 <= q0; k0 += 32) {
      // S^T[k][q] over d=128
      f32x16 s = {};
#pragma unroll
      for (int db = 0; db < 8; db++)
        s = __builtin_amdgcn_mfma_f32_32x32x16_bf16(kf[db], qf[db], s, 0, 0, 0);
      // prefetch next K tile
      if (k0 + 32 <= q0) {
#pragma unroll
        for (int db = 0; db < 8; db++)
          kf[db] = *(const short8*)&Kb[(size_t)(k0 + 32 + col) * C_ + db * 16 + hi * 8];
      }
      // V loads early (used after softmax)
      short8 va[4][2];
#pragma unroll
      for (int dblk = 0; dblk < 4; dblk++)
#pragma unroll
        for (int j = 0; j < 2; j++)
          va[dblk][j] = *(const short8*)&Vb[(size_t)(dblk * 32 + col) * T_ + k0 + j * 16 + hi * 8];

      // scale + causal mask. k-row of reg r: k0 + (r&3)+8*(r>>2)+4*hi
      const bool domask = (k0 + 31 > q0);
      if (domask) {
#pragma unroll
        for (int r = 0; r < 16; r++) {
          int krow = k0 + ((r & 3) + 8 * (r >> 2)) + hioff;
          float v = s[r] * sc;
          s[r] = (krow > qcol) ? -1e30f : v;
        }
      } else {
#pragma unroll
        for (int r = 0; r < 16; r++) s[r] = s[r] * sc;
      }
      // row max: 15 in-register + 1 xor32
      float tm = s[0];
#pragma unroll
      for (int r = 1; r < 16; r++) tm = fmaxf(tm, s[r]);
      tm = fmaxf(tm, __shfl_xor(tm, 32, 64));
      // online-softmax with defer-max (T13)
      if (!__all(tm <= m + 8.0f)) {
        float mn = fmaxf(m, tm);
        float corr = EXP2(m - mn);
        m = mn;
        l *= corr;
#pragma unroll
        for (int r = 0; r < 16; r++) { o0[r] *= corr; o1[r] *= corr; o2[r] *= corr; o3[r] *= corr; }
      }
#pragma unroll
      for (int r = 0; r < 16; r++) s[r] = EXP2(s[r] - m);
      float rs = s[0];
#pragma unroll
      for (int r = 1; r < 16; r++) rs += s[r];
      rs += __shfl_xor(rs, 32, 64);
      l += rs;
      // P^T B-frags via cvt_pk + permlane32_swap (T12 derivation)
      uint c0 = cvtpk(s[0], s[1]),  c1 = cvtpk(s[2], s[3]);
      uint c2 = cvtpk(s[4], s[5]),  c3 = cvtpk(s[6], s[7]);
      uint c4 = cvtpk(s[8], s[9]),  c5 = cvtpk(s[10], s[11]);
      uint c6 = cvtpk(s[12], s[13]), c7 = cvtpk(s[14], s[15]);
      pl32swap(c0, c2); pl32swap(c1, c3);
      pl32swap(c4, c6); pl32swap(c5, c7);
      union { uint u[4]; short8 v; } pb0, pb1;
      pb0.u[0] = c0; pb0.u[1] = c1; pb0.u[2] = c2; pb0.u[3] = c3;
      pb1.u[0] = c4; pb1.u[1] = c5; pb1.u[2] = c6; pb1.u[3] = c7;
      // PV: O^T[d][q] += V^T[d][k] P^T[k][q]
      o0 = __builtin_amdgcn_mfma_f32_32x32x16_bf16(va[0][0], pb0.v, o0, 0, 0, 0);
      o1 = __builtin_amdgcn_mfma_f32_32x32x16_bf16(va[1][0], pb0.v, o1, 0, 0, 0);
      o2 = __builtin_amdgcn_mfma_f32_32x32x16_bf16(va[2][0], pb0.v, o2, 0, 0, 0);
      o3 = __builtin_amdgcn_mfma_f32_32x32x16_bf16(va[3][0], pb0.v, o3, 0, 0, 0);
      o0 = __builtin_amdgcn_mfma_f32_32x32x16_bf16(va[0][1], pb1.v, o0, 0, 0, 0);
      o1 = __builtin_amdgcn_mfma_f32_32x32x16_bf16(va[1][1], pb1.v, o1, 0, 0, 0);
      o2 = __builtin_amdgcn_mfma_f32_32x32x16_bf16(va[2][1], pb1.v, o2, 0, 0, 0);
      o3 = __builtin_amdgcn_mfma_f32_32x32x16_bf16(va[3][1], pb1.v, o3, 0, 0, 0);
    }
    // epilogue: O^T C-layout: col=q, row(within dblk) = (r&3)+8*(r>>2)+4*hi
    float inv = 1.0f / l;
    size_t rowbase = (size_t)(b * T_ + qcol) * C_ + h * HD;
#pragma unroll
    for (int r = 0; r < 16; r++) {
      int d = (r & 3) + 8 * (r >> 2) + hioff;
      AO[rowbase + d]      = f2b(o0[r] * inv);
      AO[rowbase + 32 + d] = f2b(o1[r] * inv);
      AO[rowbase + 64 + d] = f2b(o2[r] * inv);
      AO[rowbase + 96 + d] = f2b(o3[r] * inv);
    }
  }
}

extern "C" void kernel_launch(void* const* d_in, const int* in_sizes, int n_in,
                              void* d_out, int out_size, void* d_ws, size_t ws_size,
                              hipStream_t stream) {
  const float* x  = (const float*)d_in[0];
  // d_in[1] = mask (causal tril) — implicit in the kernel
  const float* wq = (const float*)d_in[2];
  const float* wk = (const float*)d_in[3];
  const float* wv = (const float*)d_in[4];
  const float* wo = (const float*)d_in[5];

  char* ws = (char*)d_ws;
  size_t off = 0;
  auto alloc = [&](size_t bytes) { char* p = ws + off; off += (bytes + 255) & ~255ull; return p; };
  ushort_t* Qb  = (ushort_t*)alloc((size_t)M_ * C_ * 2);
  ushort_t* Kb  = (ushort_t*)alloc((size_t)M_ * C_ * 2);
  ushort_t* Vb  = (ushort_t*)alloc((size_t)M_ * C_ * 2);
  ushort_t* Vtb = (ushort_t*)alloc((size_t)M_ * C_ * 2);
  ushort_t* xb  = (ushort_t*)alloc((size_t)M_ * C_ * 2);
  ushort_t* AO  = xb;  // alias: xb dead after QKV GEMM
  ushort_t* wqt = (ushort_t*)alloc((size_t)C_ * C_ * 2);
  ushort_t* wkt = (ushort_t*)alloc((size_t)C_ * C_ * 2);
  ushort_t* wvt = (ushort_t*)alloc((size_t)C_ * C_ * 2);
  ushort_t* wot = (ushort_t*)alloc((size_t)C_ * C_ * 2);
  float* cs = (float*)alloc((size_t)T_ * 64 * 4);
  float* sn = (float*)alloc((size_t)T_ * 64 * 4);

  // 1. x -> bf16
  cvt_f32_bf16<<<(M_ * C_ / 4 + 255) / 256, 256, 0, stream>>>(x, xb, M_ * C_ / 4);
  // 2. weights -> bf16 transposed (N,K)
  dim3 tg(C_ / 64, C_ / 64);
  transpose_to_bf16<1><<<tg, 256, 0, stream>>>(wq, wqt, C_, C_);
  transpose_to_bf16<1><<<tg, 256, 0, stream>>>(wk, wkt, C_, C_);
  transpose_to_bf16<1><<<tg, 256, 0, stream>>>(wv, wvt, C_, C_);
  transpose_to_bf16<1><<<tg, 256, 0, stream>>>(wo, wot, C_, C_);
  // 3. RoPE tables
  rope_table<<<T_ * 64 / 256, 256, 0, stream>>>(cs, sn);
  // 4. QKV projections (256^2 pipelined GEMM, 128 KiB dynamic LDS)
  gemm_bt256<0><<<dim3(C_ / 256, M_ / 256, 3), 512, 131072, stream>>>(
      xb, wqt, wkt, wvt, Qb, Kb, Vb, C_, C_);
  // 5. RoPE on Q, K
  rope_apply<<<M_ * C_ / 8 / 256, 256, 0, stream>>>(Qb, Kb, cs, sn);
  // 6. V -> Vt per batch (2048x2048 transpose each)
  for (int b = 0; b < B_; b++)
    transpose_to_bf16<0><<<dim3(T_ / 64, T_ / 64), 256, 0, stream>>>(
        Vb + (size_t)b * T_ * C_, Vtb + (size_t)b * T_ * C_, T_, C_);
  // 7. flash attention v3 (swapped-QK 32x32, in-register softmax)
  flash_attn3<<<dim3(B_ * NH * 32), 64, 0, stream>>>(Qb, Kb, Vtb, AO);
  // 8. output projection -> fp32 d_out
  gemm_bt256<1><<<dim3(C_ / 256, M_ / 256, 1), 512, 131072, stream>>>(
      AO, wot, wot, wot, d_out, d_out, d_out, C_, C_);
  (void)in_sizes; (void)n_in; (void)out_size; (void)ws_size;
}

// Round 8
// 456.670 us; speedup vs baseline: 1.9291x; 1.0541x over previous
//
#include <hip/hip_runtime.h>
#include <stdint.h>

#define B_  2
#define T_  2048
#define C_  2048
#define NH  16
#define HD  128
#define M_  (B_*T_)   // 4096

typedef unsigned short ushort_t;
typedef unsigned int uint;
typedef __attribute__((ext_vector_type(8))) short short8;
typedef __attribute__((ext_vector_type(4))) float f32x4;
typedef __attribute__((ext_vector_type(16))) float f32x16;

#if __has_builtin(__builtin_amdgcn_exp2f)
#define EXP2 __builtin_amdgcn_exp2f
#else
#define EXP2 exp2f
#endif

__device__ inline ushort_t f2b(float f) {
  union { float f; unsigned u; } x; x.f = f;
  unsigned r = (x.u + 0x7fffu + ((x.u >> 16) & 1u)) >> 16;
  return (ushort_t)r;
}
__device__ inline float b2f(ushort_t b) {
  union { unsigned u; float f; } x; x.u = ((unsigned)b) << 16;
  return x.f;
}
__device__ inline uint cvtpk(float lo, float hi) {
  uint d;
  asm("v_cvt_pk_bf16_f32 %0, %1, %2" : "=v"(d) : "v"(lo), "v"(hi));
  return d;
}
__device__ inline void pl32swap(uint& a, uint& b) {
  asm volatile("v_permlane32_swap_b32 %0, %1" : "+v"(a), "+v"(b));
}
__device__ inline void gload_lds16(const void* g, void* l) {
  __builtin_amdgcn_global_load_lds((const __attribute__((address_space(1))) void*)g,
                                   (__attribute__((address_space(3))) void*)l, 16, 0, 0);
}

// ---------------- x fp32 -> bf16 ----------------
__global__ __launch_bounds__(256) void cvt_f32_bf16(const float* __restrict__ in,
                                                    ushort_t* __restrict__ out, int n4) {
  int i = blockIdx.x * 256 + threadIdx.x;
  if (i >= n4) return;
  float4 v = ((const float4*)in)[i];
  unsigned long long pk = (unsigned long long)f2b(v.x)
                        | ((unsigned long long)f2b(v.y) << 16)
                        | ((unsigned long long)f2b(v.z) << 32)
                        | ((unsigned long long)f2b(v.w) << 48);
  ((unsigned long long*)out)[i] = pk;
}

// ---------------- transpose (+convert) to bf16, out[(col)*rows + row], vector IO ----------------
template<int FROM_F32>
__global__ __launch_bounds__(256) void transpose_to_bf16(const void* __restrict__ inv,
                                                         ushort_t* __restrict__ out,
                                                         int rows, int cols) {
  __shared__ __align__(16) ushort_t tile[64][72];
  const int t = threadIdx.x;
  const int br = blockIdx.y * 64, bc = blockIdx.x * 64;
  if (FROM_F32) {
    const float* in = (const float*)inv;
    const int vc = t & 15, r0 = t >> 4;   // 4-col groups
#pragma unroll
    for (int i = 0; i < 4; i++) {
      int row = r0 + 16 * i;
      float4 v = *(const float4*)&in[(size_t)(br + row) * cols + bc + vc * 4];
      tile[row][vc * 4 + 0] = f2b(v.x);
      tile[row][vc * 4 + 1] = f2b(v.y);
      tile[row][vc * 4 + 2] = f2b(v.z);
      tile[row][vc * 4 + 3] = f2b(v.w);
    }
  } else {
    const ushort_t* in = (const ushort_t*)inv;
    const int vc = t & 7, r0 = t >> 3;    // 8-col groups
#pragma unroll
    for (int i = 0; i < 2; i++) {
      int row = r0 + 32 * i;
      short8 v = *(const short8*)&in[(size_t)(br + row) * cols + bc + vc * 8];
#pragma unroll
      for (int j = 0; j < 8; j++) tile[row][vc * 8 + j] = (ushort_t)v[j];
    }
  }
  __syncthreads();
  const int oc = t >> 2;                   // output row = orig col, 0..63
#pragma unroll
  for (int s2 = 0; s2 < 2; s2++) {
    int seg = (t & 3) + 4 * s2;            // 8-orig-row group
    short8 w;
#pragma unroll
    for (int j = 0; j < 8; j++) w[j] = (short)tile[seg * 8 + j][oc];
    *(short8*)&out[(size_t)(bc + oc) * rows + br + seg * 8] = w;
  }
}

// ---------------- RoPE cos/sin table: [T_][64] ----------------
__global__ __launch_bounds__(256) void rope_table(float* __restrict__ cs, float* __restrict__ sn) {
  int i = blockIdx.x * 256 + threadIdx.x;   // T_*64
  int tt = i >> 6, f = i & 63;
  float inv = powf(10000.0f, -(float)(2 * f) / 128.0f);
  float ang = (float)tt * inv;
  cs[i] = cosf(ang);
  sn[i] = sinf(ang);
}

// ---------------- RoPE apply in place on Q and K (bf16), vectorized ----------------
__global__ __launch_bounds__(256) void rope_apply(ushort_t* __restrict__ Q, ushort_t* __restrict__ K,
                                                  const float* __restrict__ cs,
                                                  const float* __restrict__ sn) {
  int i = blockIdx.x * 256 + threadIdx.x;   // M_*C_/8 groups of 8 elems (4 pairs)
  int row = i >> 8, g = i & 255;
  int tt = row & (T_ - 1);
  int fb = (g * 4) & 63;
  f32x4 cv = *(const f32x4*)&cs[(tt << 6) + fb];
  f32x4 sv = *(const f32x4*)&sn[(tt << 6) + fb];
  size_t idx = ((size_t)row << 11) + (size_t)g * 8;
  short8 q = *(const short8*)&Q[idx];
  short8 k = *(const short8*)&K[idx];
#pragma unroll
  for (int j = 0; j < 4; j++) {
    float c = cv[j], s = sv[j];
    float qr = b2f((ushort_t)q[2 * j]), qi = b2f((ushort_t)q[2 * j + 1]);
    q[2 * j]     = (short)f2b(qr * c - qi * s);
    q[2 * j + 1] = (short)f2b(qr * s + qi * c);
    float kr = b2f((ushort_t)k[2 * j]), ki = b2f((ushort_t)k[2 * j + 1]);
    k[2 * j]     = (short)f2b(kr * c - ki * s);
    k[2 * j + 1] = (short)f2b(kr * s + ki * c);
  }
  *(short8*)&Q[idx] = q;
  *(short8*)&K[idx] = k;
}

// ---------------- GEMM v3: BM=256 x BN=128, BK=64, 8 waves (4Mx2N), 3-deep LDS pipeline ----------------
// C[M,N] = A[M,K] @ Bt[N,K]^T, bf16 in, bf16/f32 out.
// LDS 144 KiB = 3 bufs x (A 256x64 + B 128x64) bf16, 16B-chunk XOR swizzle (chunk ^= row&7)
// applied on the GLOBAL source (linear LDS dest) and on the ds_read address.
// Pipeline: tile j lives in buf j%3; iter t stages tile t+2 then waits vmcnt(12) — tile t's
// 6 loads are the oldest of 18 in flight, issued 2 iterations ago -> wait is free; loads
// never drain in the main loop (T3/T4). setprio around MFMA cluster (T5).
template<int OUTF32>
__global__ __launch_bounds__(512, 2) void gemm_bt3(const ushort_t* __restrict__ A,
                                                   const ushort_t* __restrict__ Bt0,
                                                   const ushort_t* __restrict__ Bt1,
                                                   const ushort_t* __restrict__ Bt2,
                                                   void* __restrict__ O0, void* __restrict__ O1,
                                                   void* __restrict__ O2, int N, int K) {
  extern __shared__ __align__(16) ushort_t lds[];   // 3 * 24576 elems = 144 KiB
  const int z = blockIdx.z;
  const ushort_t* Bt = (z == 0) ? Bt0 : (z == 1) ? Bt1 : Bt2;
  void* Ov = (z == 0) ? O0 : (z == 1) ? O1 : O2;
  const int tid = threadIdx.x;
  const int lane = tid & 63, wave = tid >> 6;
  const int lr = lane & 15, lg = lane >> 4;
  const int wm = wave >> 1, wn = wave & 1;          // 4 M-waves x 2 N-waves
  const int swz = lr & 7;
  const int bm = blockIdx.y, bn = blockIdx.x;
  const ushort_t* Ap = A + (size_t)bm * 256 * K;
  const ushort_t* Bp = Bt + (size_t)bn * 128 * K;
  const int NT = K >> 6;

  f32x4 acc[4][4] = {};

  // stage one K-tile: A 2048 chunks (4/thread) + B 1024 chunks (2/thread), 16B each
  auto stage = [&](int k0, int buf) {
    const int base = buf * 24576;
#pragma unroll
    for (int i = 0; i < 4; i++) {
      int idx = i * 512 + tid;
      int row = idx >> 3;
      int c = (idx & 7) ^ (row & 7);                 // inverse-swizzled source chunk
      gload_lds16(Ap + (size_t)row * K + k0 + c * 8, &lds[(size_t)(base + idx * 8)]);
    }
#pragma unroll
    for (int i = 0; i < 2; i++) {
      int idx = i * 512 + tid;
      int row = idx >> 3;
      int c = (idx & 7) ^ (row & 7);
      gload_lds16(Bp + (size_t)row * K + k0 + c * 8, &lds[(size_t)(base + 16384 + idx * 8)]);
    }
  };

  stage(0, 0);
  stage(64, 1);

  for (int t = 0; t < NT; t++) {
    if (t + 2 < NT) stage((t + 2) << 6, (t + 2) % 3);
    if (t < NT - 2)       asm volatile("s_waitcnt vmcnt(12)" ::: "memory");
    else if (t == NT - 2) asm volatile("s_waitcnt vmcnt(6)"  ::: "memory");
    else                  asm volatile("s_waitcnt vmcnt(0)"  ::: "memory");
    __builtin_amdgcn_s_barrier();                    // tile t visible to all waves
    const int abase = (t % 3) * 24576, bbase = abase + 16384;
    __builtin_amdgcn_s_setprio(1);
#pragma unroll
    for (int kk = 0; kk < 2; kk++) {
      short8 af[4], bf[4];
      const int ch = ((kk * 4 + lg) ^ swz) * 8;
#pragma unroll
      for (int mf = 0; mf < 4; mf++)
        af[mf] = *(const short8*)&lds[abase + (wm * 64 + mf * 16 + lr) * 64 + ch];
#pragma unroll
      for (int nf = 0; nf < 4; nf++)
        bf[nf] = *(const short8*)&lds[bbase + (wn * 64 + nf * 16 + lr) * 64 + ch];
#pragma unroll
      for (int mf = 0; mf < 4; mf++)
#pragma unroll
        for (int nf = 0; nf < 4; nf++)
          acc[mf][nf] = __builtin_amdgcn_mfma_f32_16x16x32_bf16(af[mf], bf[nf], acc[mf][nf], 0, 0, 0);
    }
    __builtin_amdgcn_s_setprio(0);
    __builtin_amdgcn_s_barrier();                    // close reads of buf t%3
  }

  const int row0 = bm * 256 + wm * 64 + lg * 4;
  const int col0 = bn * 128 + wn * 64 + lr;
  if (OUTF32) {
    float* O = (float*)Ov;
#pragma unroll
    for (int mf = 0; mf < 4; mf++)
#pragma unroll
      for (int nf = 0; nf < 4; nf++)
#pragma unroll
        for (int r = 0; r < 4; r++)
          O[(size_t)(row0 + mf * 16 + r) * N + col0 + nf * 16] = acc[mf][nf][r];
  } else {
    ushort_t* O = (ushort_t*)Ov;
#pragma unroll
    for (int mf = 0; mf < 4; mf++)
#pragma unroll
      for (int nf = 0; nf < 4; nf++)
#pragma unroll
        for (int r = 0; r < 4; r++)
          O[(size_t)(row0 + mf * 16 + r) * N + col0 + nf * 16] = f2b(acc[mf][nf][r]);
  }
}

// ---------------- Flash attention v3: swapped-QK 32x32, in-register softmax ----------------
// 1024 blocks x 64 threads (1 wave). Wave handles q-tile pair {widx, 63-widx} (32 rows each)
// -> uniform 65 KV-32 steps. S^T = mfma32x32x16(K, Q); lane owns q=lane&31, 16 of 32 k-scores;
// softmax in-register + one shfl_xor(32). P->A-frag via cvt_pk_bf16 + permlane32_swap (T12).
// O^T accumulated via mfma(V^T, P^T); Vt layout [d][t] per (b,h).
__global__ __launch_bounds__(64) void flash_attn3(const ushort_t* __restrict__ Q,
                                                  const ushort_t* __restrict__ K,
                                                  const ushort_t* __restrict__ Vt,
                                                  ushort_t* __restrict__ AO) {
  // XCD swizzle: 1024 blocks -> 128 consecutive per XCD (4 bh's K/V colocate in L2)
  int flat = blockIdx.x;
  int swz = (flat & 7) * 128 + (flat >> 3);
  const int bh = swz >> 5, widx = swz & 31;
  const int b = bh >> 4, h = bh & 15;
  const int lane = threadIdx.x & 63;
  const int col = lane & 31, hi = lane >> 5, hioff = 4 * hi;
  const ushort_t* Qb = Q + (size_t)b * T_ * C_ + (size_t)h * HD;
  const ushort_t* Kb = K + (size_t)b * T_ * C_ + (size_t)h * HD;
  const ushort_t* Vb = Vt + (size_t)bh * (size_t)HD * T_;
  const float sc = 0.12754245f;  // log2(e)/sqrt(128)

#pragma unroll 1
  for (int ph = 0; ph < 2; ph++) {
    const int tile = ph ? (63 - widx) : widx;
    const int q0 = tile * 32;
    const int qcol = q0 + col;
    // Q B-fragments: lane holds Q[q0+col][db*16 + hi*8 + e]
    short8 qf[8];
#pragma unroll
    for (int db = 0; db < 8; db++)
      qf[db] = *(const short8*)&Qb[(size_t)qcol * C_ + db * 16 + hi * 8];

    f32x16 o0 = {}, o1 = {}, o2 = {}, o3 = {};
    float m = -1e30f, l = 0.f;

    // preload K for k0=0
    short8 kf[8];
#pragma unroll
    for (int db = 0; db < 8; db++)
      kf[db] = *(const short8*)&Kb[(size_t)col * C_ + db * 16 + hi * 8];

#pragma unroll 1
    for (int k0 = 0; k0 <= q0; k0 += 32) {
      // S^T[k][q] over d=128
      f32x16 s = {};
#pragma unroll
      for (int db = 0; db < 8; db++)
        s = __builtin_amdgcn_mfma_f32_32x32x16_bf16(kf[db], qf[db], s, 0, 0, 0);
      // prefetch next K tile
      if (k0 + 32 <= q0) {
#pragma unroll
        for (int db = 0; db < 8; db++)
          kf[db] = *(const short8*)&Kb[(size_t)(k0 + 32 + col) * C_ + db * 16 + hi * 8];
      }
      // V loads early (used after softmax)
      short8 va[4][2];
#pragma unroll
      for (int dblk = 0; dblk < 4; dblk++)
#pragma unroll
        for (int j = 0; j < 2; j++)
          va[dblk][j] = *(const short8*)&Vb[(size_t)(dblk * 32 + col) * T_ + k0 + j * 16 + hi * 8];

      // scale + causal mask. k-row of reg r: k0 + (r&3)+8*(r>>2)+4*hi
      const bool domask = (k0 + 31 > q0);
      if (domask) {
#pragma unroll
        for (int r = 0; r < 16; r++) {
          int krow = k0 + ((r & 3) + 8 * (r >> 2)) + hioff;
          float v = s[r] * sc;
          s[r] = (krow > qcol) ? -1e30f : v;
        }
      } else {
#pragma unroll
        for (int r = 0; r < 16; r++) s[r] = s[r] * sc;
      }
      // row max: 15 in-register + 1 xor32
      float tm = s[0];
#pragma unroll
      for (int r = 1; r < 16; r++) tm = fmaxf(tm, s[r]);
      tm = fmaxf(tm, __shfl_xor(tm, 32, 64));
      // online-softmax with defer-max (T13)
      if (!__all(tm <= m + 8.0f)) {
        float mn = fmaxf(m, tm);
        float corr = EXP2(m - mn);
        m = mn;
        l *= corr;
#pragma unroll
        for (int r = 0; r < 16; r++) { o0[r] *= corr; o1[r] *= corr; o2[r] *= corr; o3[r] *= corr; }
      }
#pragma unroll
      for (int r = 0; r < 16; r++) s[r] = EXP2(s[r] - m);
      float rs = s[0];
#pragma unroll
      for (int r = 1; r < 16; r++) rs += s[r];
      rs += __shfl_xor(rs, 32, 64);
      l += rs;
      // P^T B-frags via cvt_pk + permlane32_swap (T12 derivation)
      uint c0 = cvtpk(s[0], s[1]),  c1 = cvtpk(s[2], s[3]);
      uint c2 = cvtpk(s[4], s[5]),  c3 = cvtpk(s[6], s[7]);
      uint c4 = cvtpk(s[8], s[9]),  c5 = cvtpk(s[10], s[11]);
      uint c6 = cvtpk(s[12], s[13]), c7 = cvtpk(s[14], s[15]);
      pl32swap(c0, c2); pl32swap(c1, c3);
      pl32swap(c4, c6); pl32swap(c5, c7);
      union { uint u[4]; short8 v; } pb0, pb1;
      pb0.u[0] = c0; pb0.u[1] = c1; pb0.u[2] = c2; pb0.u[3] = c3;
      pb1.u[0] = c4; pb1.u[1] = c5; pb1.u[2] = c6; pb1.u[3] = c7;
      // PV: O^T[d][q] += V^T[d][k] P^T[k][q]
      o0 = __builtin_amdgcn_mfma_f32_32x32x16_bf16(va[0][0], pb0.v, o0, 0, 0, 0);
      o1 = __builtin_amdgcn_mfma_f32_32x32x16_bf16(va[1][0], pb0.v, o1, 0, 0, 0);
      o2 = __builtin_amdgcn_mfma_f32_32x32x16_bf16(va[2][0], pb0.v, o2, 0, 0, 0);
      o3 = __builtin_amdgcn_mfma_f32_32x32x16_bf16(va[3][0], pb0.v, o3, 0, 0, 0);
      o0 = __builtin_amdgcn_mfma_f32_32x32x16_bf16(va[0][1], pb1.v, o0, 0, 0, 0);
      o1 = __builtin_amdgcn_mfma_f32_32x32x16_bf16(va[1][1], pb1.v, o1, 0, 0, 0);
      o2 = __builtin_amdgcn_mfma_f32_32x32x16_bf16(va[2][1], pb1.v, o2, 0, 0, 0);
      o3 = __builtin_amdgcn_mfma_f32_32x32x16_bf16(va[3][1], pb1.v, o3, 0, 0, 0);
    }
    // epilogue: O^T C-layout: col=q, row(within dblk) = (r&3)+8*(r>>2)+4*hi
    float inv = 1.0f / l;
    size_t rowbase = (size_t)(b * T_ + qcol) * C_ + h * HD;
#pragma unroll
    for (int r = 0; r < 16; r++) {
      int d = (r & 3) + 8 * (r >> 2) + hioff;
      AO[rowbase + d]      = f2b(o0[r] * inv);
      AO[rowbase + 32 + d] = f2b(o1[r] * inv);
      AO[rowbase + 64 + d] = f2b(o2[r] * inv);
      AO[rowbase + 96 + d] = f2b(o3[r] * inv);
    }
  }
}

extern "C" void kernel_launch(void* const* d_in, const int* in_sizes, int n_in,
                              void* d_out, int out_size, void* d_ws, size_t ws_size,
                              hipStream_t stream) {
  const float* x  = (const float*)d_in[0];
  // d_in[1] = mask (causal tril) — implicit in the kernel
  const float* wq = (const float*)d_in[2];
  const float* wk = (const float*)d_in[3];
  const float* wv = (const float*)d_in[4];
  const float* wo = (const float*)d_in[5];

  char* ws = (char*)d_ws;
  size_t off = 0;
  auto alloc = [&](size_t bytes) { char* p = ws + off; off += (bytes + 255) & ~255ull; return p; };
  ushort_t* Qb  = (ushort_t*)alloc((size_t)M_ * C_ * 2);
  ushort_t* Kb  = (ushort_t*)alloc((size_t)M_ * C_ * 2);
  ushort_t* Vb  = (ushort_t*)alloc((size_t)M_ * C_ * 2);
  ushort_t* Vtb = (ushort_t*)alloc((size_t)M_ * C_ * 2);
  ushort_t* xb  = (ushort_t*)alloc((size_t)M_ * C_ * 2);
  ushort_t* AO  = xb;  // alias: xb dead after QKV GEMM
  ushort_t* wqt = (ushort_t*)alloc((size_t)C_ * C_ * 2);
  ushort_t* wkt = (ushort_t*)alloc((size_t)C_ * C_ * 2);
  ushort_t* wvt = (ushort_t*)alloc((size_t)C_ * C_ * 2);
  ushort_t* wot = (ushort_t*)alloc((size_t)C_ * C_ * 2);
  float* cs = (float*)alloc((size_t)T_ * 64 * 4);
  float* sn = (float*)alloc((size_t)T_ * 64 * 4);

  // 1. x -> bf16
  cvt_f32_bf16<<<(M_ * C_ / 4 + 255) / 256, 256, 0, stream>>>(x, xb, M_ * C_ / 4);
  // 2. weights -> bf16 transposed (N,K)
  dim3 tg(C_ / 64, C_ / 64);
  transpose_to_bf16<1><<<tg, 256, 0, stream>>>(wq, wqt, C_, C_);
  transpose_to_bf16<1><<<tg, 256, 0, stream>>>(wk, wkt, C_, C_);
  transpose_to_bf16<1><<<tg, 256, 0, stream>>>(wv, wvt, C_, C_);
  transpose_to_bf16<1><<<tg, 256, 0, stream>>>(wo, wot, C_, C_);
  // 3. RoPE tables
  rope_table<<<T_ * 64 / 256, 256, 0, stream>>>(cs, sn);
  // 4. QKV projections (256x128 3-deep pipelined GEMM, 144 KiB dynamic LDS, 768 blocks = 3 rounds)
  gemm_bt3<0><<<dim3(C_ / 128, M_ / 256, 3), 512, 147456, stream>>>(
      xb, wqt, wkt, wvt, Qb, Kb, Vb, C_, C_);
  // 5. RoPE on Q, K
  rope_apply<<<M_ * C_ / 8 / 256, 256, 0, stream>>>(Qb, Kb, cs, sn);
  // 6. V -> Vt per batch (2048x2048 transpose each)
  for (int b = 0; b < B_; b++)
    transpose_to_bf16<0><<<dim3(T_ / 64, T_ / 64), 256, 0, stream>>>(
        Vb + (size_t)b * T_ * C_, Vtb + (size_t)b * T_ * C_, T_, C_);
  // 7. flash attention v3 (swapped-QK 32x32, in-register softmax)
  flash_attn3<<<dim3(B_ * NH * 32), 64, 0, stream>>>(Qb, Kb, Vtb, AO);
  // 8. output projection -> fp32 d_out (256 blocks = 1 full round)
  gemm_bt3<1><<<dim3(C_ / 128, M_ / 256, 1), 512, 147456, stream>>>(
      AO, wot, wot, wot, d_out, d_out, d_out, C_, C_);
  (void)in_sizes; (void)n_in; (void)out_size; (void)ws_size;
}